// Round 1
// baseline (1302.553 us; speedup 1.0000x reference)
//
#include <hip/hip_runtime.h>
#include <hip/hip_bf16.h>
#include <math.h>

// Problem constants (from reference)
#define Bb 32
#define Vv 50
#define Cc 64
#define Ee 256
#define Aa 128
#define Hh 256
#define Ll 10
#define BVn (Bb*Vv)          // 1600
#define SCALE 0.08838834764831845f   // 1/sqrt(128)

__device__ __forceinline__ float sigmoidf_(float x) {
    return 1.0f / (1.0f + __expf(-x));
}

// ---------------------------------------------------------------------------
// Kernel 1: per-(b,v) attention + gated pooling -> vv[v][b][e]  (fp32)
// One block per n = b*V+v.  LDS ~148KB, 256 threads.
// ---------------------------------------------------------------------------
__global__ __launch_bounds__(256) void attn_kernel(
    const int*   __restrict__ codes,      // [B,V,C]
    const float* __restrict__ mask,       // [B,V,C] 0 or 1e20
    const float* __restrict__ tvals,      // [B,V]
    const float* __restrict__ emb_table,  // [VOCAB+1, E]
    const float* __restrict__ WQ1,        // [A,E]
    const float* __restrict__ WK1,        // [A,E]
    const float* __restrict__ decay,      // [VOCAB+1]
    const float* __restrict__ initial,    // [VOCAB+1]
    float*       __restrict__ vv)         // [V][B][E]
{
    __shared__ float emb_s[Cc * 260];      // stride 260: 16B-aligned rows
    __shared__ float q_s[Cc * 129];        // stride 129: conflict-friendly
    __shared__ float k_s[Cc * 129];
    __shared__ float wstage[4352];         // wq[128*17], wk[128*17]; reused as d_s[64*65]
    __shared__ int   codes_l[Cc];
    __shared__ float maskcol_s[Cc];
    __shared__ float coef_s[Cc];
    __shared__ float wsum_s[Cc];

    const int n   = blockIdx.x;
    const int tid = threadIdx.x;
    const int b   = n / Vv;
    const int v   = n - b * Vv;

    if (tid < Cc) {
        codes_l[tid]   = codes[n * Cc + tid];
        maskcol_s[tid] = mask[n * Cc + tid];
    }
    __syncthreads();

    // gather emb rows (padding code 0 -> zero row in table)
    for (int idx = tid; idx < Cc * Ee; idx += 256) {
        int c = idx >> 8, e = idx & 255;
        emb_s[c * 260 + e] = emb_table[codes_l[c] * Ee + e];
    }

    const int tx = tid & 15, ty = tid >> 4;
    float* wq_s = wstage;          // [128][17]
    float* wk_s = wstage + 2176;   // [128][17]

    float qacc[4][8] = {};
    float kacc[4][8] = {};

    // Q = emb@WQ1^T, K = emb@WK1^T   (k-chunked W staging in LDS)
    for (int kc = 0; kc < Ee; kc += 16) {
        __syncthreads();
        for (int idx = tid; idx < 2048; idx += 256) {
            int a = idx >> 4, kk = idx & 15;
            wq_s[a * 17 + kk] = WQ1[a * Ee + kc + kk];
            wk_s[a * 17 + kk] = WK1[a * Ee + kc + kk];
        }
        __syncthreads();
#pragma unroll
        for (int kk = 0; kk < 16; ++kk) {
            float ev[4];
#pragma unroll
            for (int i = 0; i < 4; ++i)
                ev[i] = emb_s[(ty * 4 + i) * 260 + kc + kk];
#pragma unroll
            for (int j = 0; j < 8; ++j) {
                float wq = wq_s[(tx + 16 * j) * 17 + kk];
                float wk = wk_s[(tx + 16 * j) * 17 + kk];
#pragma unroll
                for (int i = 0; i < 4; ++i) {
                    qacc[i][j] = fmaf(ev[i], wq, qacc[i][j]);
                    kacc[i][j] = fmaf(ev[i], wk, kacc[i][j]);
                }
            }
        }
    }
    // store Q,K fragments
#pragma unroll
    for (int i = 0; i < 4; ++i)
#pragma unroll
        for (int j = 0; j < 8; ++j) {
            q_s[(ty * 4 + i) * 129 + tx + 16 * j] = qacc[i][j];
            k_s[(ty * 4 + i) * 129 + tx + 16 * j] = kacc[i][j];
        }
    __syncthreads();   // Q,K complete; wstage free -> becomes d_s

    // d[c][cd] = Q[c]·K[cd]; subtract column mask; scale.
    // (Row mask is a per-row constant -> softmax-invariant; omitted.)
    float* d_s = wstage;   // [64][65]
    {
        float dacc[4][4] = {};
#pragma unroll 4
        for (int a = 0; a < Aa; ++a) {
            float qv[4], kv[4];
#pragma unroll
            for (int i = 0; i < 4; ++i) qv[i] = q_s[(ty * 4 + i) * 129 + a];
#pragma unroll
            for (int j = 0; j < 4; ++j) kv[j] = k_s[(tx * 4 + j) * 129 + a];
#pragma unroll
            for (int i = 0; i < 4; ++i)
#pragma unroll
                for (int j = 0; j < 4; ++j)
                    dacc[i][j] = fmaf(qv[i], kv[j], dacc[i][j]);
        }
#pragma unroll
        for (int i = 0; i < 4; ++i)
#pragma unroll
            for (int j = 0; j < 4; ++j) {
                int c = ty * 4 + i, cd = tx * 4 + j;
                d_s[c * 65 + cd] = (dacc[i][j] - maskcol_s[cd]) * SCALE;
            }
    }
    __syncthreads();

    // row softmax: 4 threads per row
    {
        int row = tid >> 2, t4 = tid & 3;
        float mx = -3.0e38f;
#pragma unroll
        for (int m = 0; m < 16; ++m)
            mx = fmaxf(mx, d_s[row * 65 + t4 + 4 * m]);
        mx = fmaxf(mx, __shfl_xor(mx, 1));
        mx = fmaxf(mx, __shfl_xor(mx, 2));
        float sum = 0.f;
#pragma unroll
        for (int m = 0; m < 16; ++m) {
            float ex = __expf(d_s[row * 65 + t4 + 4 * m] - mx);
            d_s[row * 65 + t4 + 4 * m] = ex;
            sum += ex;
        }
        sum += __shfl_xor(sum, 1);
        sum += __shfl_xor(sum, 2);
        float inv = 1.0f / sum;
#pragma unroll
        for (int m = 0; m < 16; ++m)
            d_s[row * 65 + t4 + 4 * m] *= inv;
    }
    __syncthreads();

    // coef[c] = keep[c] * sigmoid(decay[code]*t + initial[code])
    if (tid < Cc) {
        int code = codes_l[tid];
        float keep = (maskcol_s[tid] == 0.0f) ? 1.0f : 0.0f;
        float g = decay[code] * tvals[n] + initial[code];
        coef_s[tid] = keep * sigmoidf_(g);
    }
    __syncthreads();

    // wsum[d] = sum_c coef[c]*s[c][d]
    if (tid < Cc) {
        float acc = 0.f;
#pragma unroll 8
        for (int c = 0; c < Cc; ++c)
            acc = fmaf(coef_s[c], d_s[c * 65 + tid], acc);
        wsum_s[tid] = acc;
    }
    __syncthreads();

    // vv[e] = sum_d wsum[d]*emb[d][e]
    {
        float acc = 0.f;
#pragma unroll 8
        for (int d = 0; d < Cc; ++d)
            acc = fmaf(wsum_s[d], emb_s[d * 260 + tid], acc);
        vv[(v * Bb + b) * Ee + tid] = acc;
    }
}

// ---------------------------------------------------------------------------
// Kernel 2: C[m][j] = dot(A[m,:256], W[j,:256]) + b1[j] + b2[j]
// A: [M][256], W: [1024][256], C: [M][1024]
// ---------------------------------------------------------------------------
__global__ __launch_bounds__(256) void xw_kernel(
    const float* __restrict__ A, const float* __restrict__ W,
    const float* __restrict__ b1, const float* __restrict__ b2,
    float* __restrict__ Cout, int M)
{
    __shared__ float a_s[64 * 65];
    __shared__ float w_s[64 * 65];
    const int m0 = blockIdx.x * 64, j0 = blockIdx.y * 64;
    const int tid = threadIdx.x, tx = tid & 15, ty = tid >> 4;
    float acc[4][4] = {};
    for (int kc = 0; kc < 256; kc += 64) {
        __syncthreads();
        for (int idx = tid; idx < 4096; idx += 256) {
            int r = idx >> 6, kk = idx & 63;
            int m = m0 + r;
            a_s[r * 65 + kk] = (m < M) ? A[m * 256 + kc + kk] : 0.f;
            w_s[r * 65 + kk] = W[(j0 + r) * 256 + kc + kk];
        }
        __syncthreads();
#pragma unroll 8
        for (int kk = 0; kk < 64; ++kk) {
            float av[4], wv[4];
#pragma unroll
            for (int i = 0; i < 4; ++i) av[i] = a_s[(ty * 4 + i) * 65 + kk];
#pragma unroll
            for (int j = 0; j < 4; ++j) wv[j] = w_s[(tx * 4 + j) * 65 + kk];
#pragma unroll
            for (int i = 0; i < 4; ++i)
#pragma unroll
                for (int j = 0; j < 4; ++j)
                    acc[i][j] = fmaf(av[i], wv[j], acc[i][j]);
        }
    }
#pragma unroll
    for (int i = 0; i < 4; ++i) {
        int m = m0 + ty * 4 + i;
        if (m < M) {
#pragma unroll
            for (int j = 0; j < 4; ++j) {
                int jj = j0 + tx * 4 + j;
                Cout[m * 1024 + jj] = acc[i][j] + b1[jj] + b2[jj];
            }
        }
    }
}

// ---------------------------------------------------------------------------
// Kernel 0: transpose w_hh_f [1024][256] -> w_hh_t [256][1024]
// ---------------------------------------------------------------------------
__global__ __launch_bounds__(256) void transpose_whh(
    const float* __restrict__ w, float* __restrict__ wt)
{
    int g = blockIdx.x * 256 + threadIdx.x;   // g = k*1024 + j
    int k = g >> 10, j = g & 1023;
    wt[g] = w[j * 256 + k];
}

// ---------------------------------------------------------------------------
// Kernel 3: forward LSTM recurrence (per-batch block) + backward single cell
//           + output head + softmax.  32 blocks x 512 threads.
// ---------------------------------------------------------------------------
__global__ __launch_bounds__(512) void lstm_kernel(
    const float* __restrict__ xg,      // [50][32][1024]  x@Wih_f^T + biases
    const float* __restrict__ xgb,     // [32][1024]      x_49@Wih_b^T + biases
    const float* __restrict__ w_hh_t,  // [256][1024]
    const float* __restrict__ W_out,   // [10][512]
    const float* __restrict__ b_out,   // [10]
    float*       __restrict__ out)     // [32][10]
{
    __shared__ float h_s[Hh];
    __shared__ float gates_s[4 * Hh];
    __shared__ float last_s[2 * Hh];
    __shared__ float logits_s[Ll];

    const int b = blockIdx.x, tid = threadIdx.x;
    if (tid < Hh) h_s[tid] = 0.f;
    float c_reg = 0.f;
    __syncthreads();

    const float2* w2  = (const float2*)w_hh_t;   // [256][512] of float2
    for (int t = 0; t < Vv; ++t) {
        float2 acc = *(const float2*)&xg[(t * Bb + b) * 1024 + 2 * tid];
#pragma unroll 8
        for (int k = 0; k < Hh; ++k) {
            float hk = h_s[k];
            float2 wv = w2[(k << 9) + tid];
            acc.x = fmaf(hk, wv.x, acc.x);
            acc.y = fmaf(hk, wv.y, acc.y);
        }
        gates_s[2 * tid]     = acc.x;
        gates_s[2 * tid + 1] = acc.y;
        __syncthreads();
        if (tid < Hh) {
            float ig = sigmoidf_(gates_s[tid]);
            float fg = sigmoidf_(gates_s[Hh + tid]);
            float gg = tanhf(gates_s[2 * Hh + tid]);
            float og = sigmoidf_(gates_s[3 * Hh + tid]);
            c_reg = fg * c_reg + ig * gg;
            h_s[tid] = og * tanhf(c_reg);
        }
        __syncthreads();
    }

    // backward LSTM: only first scan step matters (h=c=0 -> w_hh_b drops out)
    if (tid < Hh) {
        last_s[tid] = h_s[tid];
        float ig = sigmoidf_(xgb[b * 1024 + tid]);
        float gg = tanhf(xgb[b * 1024 + 2 * Hh + tid]);
        float og = sigmoidf_(xgb[b * 1024 + 3 * Hh + tid]);
        float cb = ig * gg;
        last_s[Hh + tid] = og * tanhf(cb);
    }
    __syncthreads();

    if (tid < Ll) {
        float acc = b_out[tid];
        for (int q = 0; q < 2 * Hh; ++q)
            acc = fmaf(last_s[q], W_out[tid * 2 * Hh + q], acc);
        logits_s[tid] = acc;
    }
    __syncthreads();
    if (tid == 0) {
        float mx = -3.0e38f;
        for (int l = 0; l < Ll; ++l) mx = fmaxf(mx, logits_s[l]);
        float ex[Ll], s = 0.f;
        for (int l = 0; l < Ll; ++l) { ex[l] = __expf(logits_s[l] - mx); s += ex[l]; }
        float inv = 1.0f / s;
        for (int l = 0; l < Ll; ++l) out[b * Ll + l] = ex[l] * inv;
    }
}

// ---------------------------------------------------------------------------
extern "C" void kernel_launch(void* const* d_in, const int* in_sizes, int n_in,
                              void* d_out, int out_size, void* d_ws, size_t ws_size,
                              hipStream_t stream) {
    const int*   codes     = (const int*)  d_in[0];
    const float* mask      = (const float*)d_in[1];
    const float* tvals     = (const float*)d_in[2];
    // d_in[3] = Mode (unused by reference)
    const float* emb_table = (const float*)d_in[4];
    const float* WQ1       = (const float*)d_in[5];
    const float* WK1       = (const float*)d_in[6];
    const float* decay     = (const float*)d_in[7];
    const float* initial   = (const float*)d_in[8];
    const float* w_ih_f    = (const float*)d_in[9];
    const float* w_hh_f    = (const float*)d_in[10];
    const float* b_ih_f    = (const float*)d_in[11];
    const float* b_hh_f    = (const float*)d_in[12];
    const float* w_ih_b    = (const float*)d_in[13];
    // d_in[14] = w_hh_b (mathematically unused: backward output = first scan step, h0=0)
    const float* b_ih_b    = (const float*)d_in[15];
    const float* b_hh_b    = (const float*)d_in[16];
    const float* W_out     = (const float*)d_in[17];
    const float* b_out     = (const float*)d_in[18];
    float* out = (float*)d_out;

    // workspace layout (floats):
    float* ws      = (float*)d_ws;
    float* vv      = ws;                        // 1600*256   = 409600
    float* xg_f    = vv + 409600;               // 1600*1024  = 1638400
    float* xgb     = xg_f + 1638400;            // 32*1024    = 32768
    float* w_hh_t  = xgb + 32768;               // 256*1024   = 262144
    // total 2342912 floats = 9.37 MB

    transpose_whh<<<1024, 256, 0, stream>>>(w_hh_f, w_hh_t);
    attn_kernel<<<BVn, 256, 0, stream>>>(codes, mask, tvals, emb_table,
                                         WQ1, WK1, decay, initial, vv);
    xw_kernel<<<dim3(25, 16), 256, 0, stream>>>(vv, w_ih_f, b_ih_f, b_hh_f,
                                                xg_f, BVn);
    xw_kernel<<<dim3(1, 16), 256, 0, stream>>>(vv + 49 * Bb * Ee, w_ih_b,
                                               b_ih_b, b_hh_b, xgb, Bb);
    lstm_kernel<<<Bb, 512, 0, stream>>>(xg_f, xgb, w_hh_t, W_out, b_out, out);
}

// Round 2
// 939.847 us; speedup vs baseline: 1.3859x; 1.3859x over previous
//
#include <hip/hip_runtime.h>
#include <hip/hip_bf16.h>
#include <math.h>

// Problem constants (from reference)
#define Bb 32
#define Vv 50
#define Cc 64
#define Ee 256
#define Aa 128
#define Hh 256
#define Ll 10
#define BVn (Bb*Vv)          // 1600
#define SCALE 0.08838834764831845f   // 1/sqrt(128)

// persistent-LSTM config
#define NB 8          // blocks
#define HS 32         // hidden units per block
#define RWS (4*HS)    // gate rows per block = 128
#define WPAD 264      // bf16 row stride (uniform-bank for ds_read_b128)
#define GPAD 132      // f32 row stride for gates scratch
#define CPAD 36       // f32 row stride for c state (16B-aligned float4 rows)

typedef __bf16 bf16x8 __attribute__((ext_vector_type(8)));
typedef float  f32x4  __attribute__((ext_vector_type(4)));

__device__ __forceinline__ float sigmoidf_(float x) {
    return 1.0f / (1.0f + __expf(-x));
}
// overflow-safe tanh via expf (inf-safe at both ends)
__device__ __forceinline__ float tanhf_(float x) {
    return 1.0f - 2.0f / (__expf(2.0f * x) + 1.0f);
}

// ---------------------------------------------------------------------------
// Kernel 1: per-(b,v) attention + gated pooling -> vv[v][b][e]  (fp32)
// ---------------------------------------------------------------------------
__global__ __launch_bounds__(256) void attn_kernel(
    const int*   __restrict__ codes,
    const float* __restrict__ mask,
    const float* __restrict__ tvals,
    const float* __restrict__ emb_table,
    const float* __restrict__ WQ1,
    const float* __restrict__ WK1,
    const float* __restrict__ decay,
    const float* __restrict__ initial,
    float*       __restrict__ vv)
{
    __shared__ float emb_s[Cc * 260];
    __shared__ float q_s[Cc * 129];
    __shared__ float k_s[Cc * 129];
    __shared__ float wstage[4352];
    __shared__ int   codes_l[Cc];
    __shared__ float maskcol_s[Cc];
    __shared__ float coef_s[Cc];
    __shared__ float wsum_s[Cc];

    const int n   = blockIdx.x;
    const int tid = threadIdx.x;
    const int b   = n / Vv;
    const int v   = n - b * Vv;

    if (tid < Cc) {
        codes_l[tid]   = codes[n * Cc + tid];
        maskcol_s[tid] = mask[n * Cc + tid];
    }
    __syncthreads();

    for (int idx = tid; idx < Cc * Ee; idx += 256) {
        int c = idx >> 8, e = idx & 255;
        emb_s[c * 260 + e] = emb_table[codes_l[c] * Ee + e];
    }

    const int tx = tid & 15, ty = tid >> 4;
    float* wq_s = wstage;
    float* wk_s = wstage + 2176;

    float qacc[4][8] = {};
    float kacc[4][8] = {};

    for (int kc = 0; kc < Ee; kc += 16) {
        __syncthreads();
        for (int idx = tid; idx < 2048; idx += 256) {
            int a = idx >> 4, kk = idx & 15;
            wq_s[a * 17 + kk] = WQ1[a * Ee + kc + kk];
            wk_s[a * 17 + kk] = WK1[a * Ee + kc + kk];
        }
        __syncthreads();
#pragma unroll
        for (int kk = 0; kk < 16; ++kk) {
            float ev[4];
#pragma unroll
            for (int i = 0; i < 4; ++i)
                ev[i] = emb_s[(ty * 4 + i) * 260 + kc + kk];
#pragma unroll
            for (int j = 0; j < 8; ++j) {
                float wq = wq_s[(tx + 16 * j) * 17 + kk];
                float wk = wk_s[(tx + 16 * j) * 17 + kk];
#pragma unroll
                for (int i = 0; i < 4; ++i) {
                    qacc[i][j] = fmaf(ev[i], wq, qacc[i][j]);
                    kacc[i][j] = fmaf(ev[i], wk, kacc[i][j]);
                }
            }
        }
    }
#pragma unroll
    for (int i = 0; i < 4; ++i)
#pragma unroll
        for (int j = 0; j < 8; ++j) {
            q_s[(ty * 4 + i) * 129 + tx + 16 * j] = qacc[i][j];
            k_s[(ty * 4 + i) * 129 + tx + 16 * j] = kacc[i][j];
        }
    __syncthreads();

    float* d_s = wstage;
    {
        float dacc[4][4] = {};
#pragma unroll 4
        for (int a = 0; a < Aa; ++a) {
            float qv[4], kv[4];
#pragma unroll
            for (int i = 0; i < 4; ++i) qv[i] = q_s[(ty * 4 + i) * 129 + a];
#pragma unroll
            for (int j = 0; j < 4; ++j) kv[j] = k_s[(tx * 4 + j) * 129 + a];
#pragma unroll
            for (int i = 0; i < 4; ++i)
#pragma unroll
                for (int j = 0; j < 4; ++j)
                    dacc[i][j] = fmaf(qv[i], kv[j], dacc[i][j]);
        }
#pragma unroll
        for (int i = 0; i < 4; ++i)
#pragma unroll
            for (int j = 0; j < 4; ++j) {
                int c = ty * 4 + i, cd = tx * 4 + j;
                d_s[c * 65 + cd] = (dacc[i][j] - maskcol_s[cd]) * SCALE;
            }
    }
    __syncthreads();

    {
        int row = tid >> 2, t4 = tid & 3;
        float mx = -3.0e38f;
#pragma unroll
        for (int m = 0; m < 16; ++m)
            mx = fmaxf(mx, d_s[row * 65 + t4 + 4 * m]);
        mx = fmaxf(mx, __shfl_xor(mx, 1));
        mx = fmaxf(mx, __shfl_xor(mx, 2));
        float sum = 0.f;
#pragma unroll
        for (int m = 0; m < 16; ++m) {
            float ex = __expf(d_s[row * 65 + t4 + 4 * m] - mx);
            d_s[row * 65 + t4 + 4 * m] = ex;
            sum += ex;
        }
        sum += __shfl_xor(sum, 1);
        sum += __shfl_xor(sum, 2);
        float inv = 1.0f / sum;
#pragma unroll
        for (int m = 0; m < 16; ++m)
            d_s[row * 65 + t4 + 4 * m] *= inv;
    }
    __syncthreads();

    if (tid < Cc) {
        int code = codes_l[tid];
        float keep = (maskcol_s[tid] == 0.0f) ? 1.0f : 0.0f;
        float g = decay[code] * tvals[n] + initial[code];
        coef_s[tid] = keep * sigmoidf_(g);
    }
    __syncthreads();

    if (tid < Cc) {
        float acc = 0.f;
#pragma unroll 8
        for (int c = 0; c < Cc; ++c)
            acc = fmaf(coef_s[c], d_s[c * 65 + tid], acc);
        wsum_s[tid] = acc;
    }
    __syncthreads();

    {
        float acc = 0.f;
#pragma unroll 8
        for (int d = 0; d < Cc; ++d)
            acc = fmaf(wsum_s[d], emb_s[d * 260 + tid], acc);
        vv[(v * Bb + b) * Ee + tid] = acc;
    }
}

// ---------------------------------------------------------------------------
// Kernel 2: C[m][j] = dot(A[m,:256], W[j,:256]) + b1[j] + b2[j]
// ---------------------------------------------------------------------------
__global__ __launch_bounds__(256) void xw_kernel(
    const float* __restrict__ A, const float* __restrict__ W,
    const float* __restrict__ b1, const float* __restrict__ b2,
    float* __restrict__ Cout, int M)
{
    __shared__ float a_s[64 * 65];
    __shared__ float w_s[64 * 65];
    const int m0 = blockIdx.x * 64, j0 = blockIdx.y * 64;
    const int tid = threadIdx.x, tx = tid & 15, ty = tid >> 4;
    float acc[4][4] = {};
    for (int kc = 0; kc < 256; kc += 64) {
        __syncthreads();
        for (int idx = tid; idx < 4096; idx += 256) {
            int r = idx >> 6, kk = idx & 63;
            int m = m0 + r;
            a_s[r * 65 + kk] = (m < M) ? A[m * 256 + kc + kk] : 0.f;
            w_s[r * 65 + kk] = W[(j0 + r) * 256 + kc + kk];
        }
        __syncthreads();
#pragma unroll 8
        for (int kk = 0; kk < 64; ++kk) {
            float av[4], wv[4];
#pragma unroll
            for (int i = 0; i < 4; ++i) av[i] = a_s[(ty * 4 + i) * 65 + kk];
#pragma unroll
            for (int j = 0; j < 4; ++j) wv[j] = w_s[(tx * 4 + j) * 65 + kk];
#pragma unroll
            for (int i = 0; i < 4; ++i)
#pragma unroll
                for (int j = 0; j < 4; ++j)
                    acc[i][j] = fmaf(av[i], wv[j], acc[i][j]);
        }
    }
#pragma unroll
    for (int i = 0; i < 4; ++i) {
        int m = m0 + ty * 4 + i;
        if (m < M) {
#pragma unroll
            for (int j = 0; j < 4; ++j) {
                int jj = j0 + tx * 4 + j;
                Cout[m * 1024 + jj] = acc[i][j] + b1[jj] + b2[jj];
            }
        }
    }
}

// ---------------------------------------------------------------------------
// init: zero the grid-sync counter (graph-replay determinism)
// ---------------------------------------------------------------------------
__global__ void init_sync(unsigned* cnt) {
    if (threadIdx.x == 0) *cnt = 0u;
}

// ---------------------------------------------------------------------------
// Kernel 3: persistent forward-LSTM. 8 blocks x 256 threads.
// Block k owns hidden units [32k, 32k+32) -> 128 gate rows, w slice in LDS
// (bf16). Per step: MFMA gate tile, nonlinearity, bf16 h exchange via
// device-scope atomics + counter grid-sync.
// ---------------------------------------------------------------------------
__global__ __launch_bounds__(256) void lstm_persist(
    const float* __restrict__ xg,     // [50][32][1024]  x@Wih^T + biases
    const float* __restrict__ w_hh,   // [1024][256] row-major (used directly)
    float*       __restrict__ last_f, // [32][256] final forward h (fp32)
    unsigned*    __restrict__ hbuf,   // [2][32][128] packed 2xbf16
    unsigned*    __restrict__ cnt)
{
    __shared__ __align__(16) __bf16 w_s[RWS * WPAD];   // 66 KB
    __shared__ __align__(16) __bf16 h_s[Bb * WPAD];    // 16.5 KB
    __shared__ __align__(16) float  g_s[Bb * GPAD];    // 16.5 KB
    __shared__ __align__(16) float  c_s[Bb * CPAD];    // 4.5 KB

    const int tid = threadIdx.x, blk = blockIdx.x;
    const int hs0 = blk * HS;

    // stage w slice (rows: [gate 0..3][unit 0..31]), fp32 -> bf16
    for (int i = tid; i < RWS * Ee; i += 256) {
        int r = i >> 8, k = i & 255;
        int grow = (r >> 5) * Hh + hs0 + (r & 31);
        w_s[r * WPAD + k] = (__bf16)w_hh[grow * Hh + k];
    }
    for (int i = tid; i < Bb * CPAD; i += 256) c_s[i] = 0.f;
    __syncthreads();

    const int l  = tid & 63, wv = tid >> 6;
    const int lr = l & 15,   lq = l >> 4;
    const int b_nl = tid >> 3, jg = tid & 7;    // nonlin: (batch, 4-unit group)

    for (int t = 0; t < Vv; ++t) {
        if (t > 0) {
            // ---- load h(t) (device-coherent) into LDS ----
            unsigned* hb = hbuf + (t & 1) * (Bb * 128);
            unsigned* hsu = (unsigned*)h_s;
            for (int i = tid; i < Bb * 128; i += 256) {
                int b = i >> 7, kp = i & 127;
                hsu[b * (WPAD / 2) + kp] =
                    __hip_atomic_load(hb + i, __ATOMIC_RELAXED, __HIP_MEMORY_SCOPE_AGENT);
            }
            __syncthreads();

            // ---- G[32][128] = h[32][256] @ w_slice^T (bf16 MFMA) ----
            f32x4 a00 = {}, a01 = {}, a10 = {}, a11 = {};
#pragma unroll
            for (int kt = 0; kt < 8; ++kt) {
                int ko = kt * 32 + lq * 8;
                bf16x8 A0 = *(const bf16x8*)&h_s[lr * WPAD + ko];
                bf16x8 A1 = *(const bf16x8*)&h_s[(16 + lr) * WPAD + ko];
                bf16x8 B0 = *(const bf16x8*)&w_s[(wv * 32 + lr) * WPAD + ko];
                bf16x8 B1 = *(const bf16x8*)&w_s[(wv * 32 + 16 + lr) * WPAD + ko];
                a00 = __builtin_amdgcn_mfma_f32_16x16x32_bf16(A0, B0, a00, 0, 0, 0);
                a01 = __builtin_amdgcn_mfma_f32_16x16x32_bf16(A0, B1, a01, 0, 0, 0);
                a10 = __builtin_amdgcn_mfma_f32_16x16x32_bf16(A1, B0, a10, 0, 0, 0);
                a11 = __builtin_amdgcn_mfma_f32_16x16x32_bf16(A1, B1, a11, 0, 0, 0);
            }
            // C layout: row(b) = lq*4+reg, col(rr) = lr  [m89-verified]
#pragma unroll
            for (int r = 0; r < 4; ++r) {
                int b0 = lq * 4 + r;
                g_s[b0 * GPAD + wv * 32 + lr]             = a00[r];
                g_s[b0 * GPAD + wv * 32 + 16 + lr]        = a01[r];
                g_s[(16 + b0) * GPAD + wv * 32 + lr]      = a10[r];
                g_s[(16 + b0) * GPAD + wv * 32 + 16 + lr] = a11[r];
            }
            __syncthreads();
        }

        // ---- nonlinearity: thread -> (b, 4 units) ----
        {
            const float* xgrow = xg + ((size_t)t * Bb + b_nl) * 1024;
            int col = hs0 + jg * 4;
            f32x4 gi = *(const f32x4*)&xgrow[0 * Hh + col];
            f32x4 gf = *(const f32x4*)&xgrow[1 * Hh + col];
            f32x4 gg = *(const f32x4*)&xgrow[2 * Hh + col];
            f32x4 go = *(const f32x4*)&xgrow[3 * Hh + col];
            if (t > 0) {
                int gb = b_nl * GPAD + jg * 4;
                gi += *(const f32x4*)&g_s[gb + 0 * HS];
                gf += *(const f32x4*)&g_s[gb + 1 * HS];
                gg += *(const f32x4*)&g_s[gb + 2 * HS];
                go += *(const f32x4*)&g_s[gb + 3 * HS];
            }
            f32x4 cv = *(const f32x4*)&c_s[b_nl * CPAD + jg * 4];
            float hnew[4];
#pragma unroll
            for (int u = 0; u < 4; ++u) {
                float iv = sigmoidf_(gi[u]);
                float fv = sigmoidf_(gf[u]);
                float gv = tanhf_(gg[u]);
                float ov = sigmoidf_(go[u]);
                float cn = fv * cv[u] + iv * gv;
                cv[u] = cn;
                hnew[u] = ov * tanhf_(cn);
            }
            *(f32x4*)&c_s[b_nl * CPAD + jg * 4] = cv;

            if (t < Vv - 1) {
                unsigned* hbo = hbuf + ((t + 1) & 1) * (Bb * 128);
                unsigned u0 =
                    ((unsigned)__builtin_bit_cast(unsigned short, (__bf16)hnew[0])) |
                    ((unsigned)__builtin_bit_cast(unsigned short, (__bf16)hnew[1]) << 16);
                unsigned u1 =
                    ((unsigned)__builtin_bit_cast(unsigned short, (__bf16)hnew[2])) |
                    ((unsigned)__builtin_bit_cast(unsigned short, (__bf16)hnew[3]) << 16);
                int base = b_nl * 128 + blk * 16 + jg * 2;
                __hip_atomic_store(hbo + base,     u0, __ATOMIC_RELAXED, __HIP_MEMORY_SCOPE_AGENT);
                __hip_atomic_store(hbo + base + 1, u1, __ATOMIC_RELAXED, __HIP_MEMORY_SCOPE_AGENT);
            } else {
                f32x4 hv = {hnew[0], hnew[1], hnew[2], hnew[3]};
                *(f32x4*)&last_f[b_nl * Hh + hs0 + jg * 4] = hv;
            }
        }

        // ---- grid sync (one per step, none after the last) ----
        if (t < Vv - 1) {
            __syncthreads();
            if (tid == 0) {
                __threadfence();
                __hip_atomic_fetch_add(cnt, 1u, __ATOMIC_RELEASE, __HIP_MEMORY_SCOPE_AGENT);
                unsigned tgt = (unsigned)(t + 1) * NB;
                int guard = 0;
                while (__hip_atomic_load(cnt, __ATOMIC_ACQUIRE, __HIP_MEMORY_SCOPE_AGENT) < tgt &&
                       ++guard < (1 << 28)) {
                    __builtin_amdgcn_s_sleep(1);
                }
                __threadfence();
            }
            __syncthreads();
        }
    }
}

// ---------------------------------------------------------------------------
// Kernel 4: tail — backward single cell + head + softmax. 32 blocks x 512.
// ---------------------------------------------------------------------------
__global__ __launch_bounds__(512) void lstm_tail(
    const float* __restrict__ last_f,  // [32][256]
    const float* __restrict__ xgb,     // [32][1024]
    const float* __restrict__ W_out,   // [10][512]
    const float* __restrict__ b_out,   // [10]
    float*       __restrict__ out)     // [32][10]
{
    __shared__ float last_s[2 * Hh];
    __shared__ float logits_s[Ll];
    const int b = blockIdx.x, tid = threadIdx.x;

    if (tid < Hh) {
        last_s[tid] = last_f[b * Hh + tid];
    } else {
        int j = tid - Hh;
        float ig = sigmoidf_(xgb[b * 1024 + j]);
        float gg = tanhf_(xgb[b * 1024 + 2 * Hh + j]);
        float og = sigmoidf_(xgb[b * 1024 + 3 * Hh + j]);
        last_s[Hh + j] = og * tanhf_(ig * gg);
    }
    __syncthreads();

    if (tid < Ll) {
        float acc = b_out[tid];
        for (int q = 0; q < 2 * Hh; ++q)
            acc = fmaf(last_s[q], W_out[tid * 2 * Hh + q], acc);
        logits_s[tid] = acc;
    }
    __syncthreads();
    if (tid == 0) {
        float mx = -3.0e38f;
        for (int ll2 = 0; ll2 < Ll; ++ll2) mx = fmaxf(mx, logits_s[ll2]);
        float ex[Ll], s = 0.f;
        for (int ll2 = 0; ll2 < Ll; ++ll2) { ex[ll2] = __expf(logits_s[ll2] - mx); s += ex[ll2]; }
        float inv = 1.0f / s;
        for (int ll2 = 0; ll2 < Ll; ++ll2) out[b * Ll + ll2] = ex[ll2] * inv;
    }
}

// ---------------------------------------------------------------------------
extern "C" void kernel_launch(void* const* d_in, const int* in_sizes, int n_in,
                              void* d_out, int out_size, void* d_ws, size_t ws_size,
                              hipStream_t stream) {
    const int*   codes     = (const int*)  d_in[0];
    const float* mask      = (const float*)d_in[1];
    const float* tvals     = (const float*)d_in[2];
    const float* emb_table = (const float*)d_in[4];
    const float* WQ1       = (const float*)d_in[5];
    const float* WK1       = (const float*)d_in[6];
    const float* decay     = (const float*)d_in[7];
    const float* initial   = (const float*)d_in[8];
    const float* w_ih_f    = (const float*)d_in[9];
    const float* w_hh_f    = (const float*)d_in[10];
    const float* b_ih_f    = (const float*)d_in[11];
    const float* b_hh_f    = (const float*)d_in[12];
    const float* w_ih_b    = (const float*)d_in[13];
    // d_in[14] = w_hh_b: unused (backward output = first scan step, h0=c0=0)
    const float* b_ih_b    = (const float*)d_in[15];
    const float* b_hh_b    = (const float*)d_in[16];
    const float* W_out     = (const float*)d_in[17];
    const float* b_out     = (const float*)d_in[18];
    float* out = (float*)d_out;

    // workspace layout (floats)
    float* ws      = (float*)d_ws;
    float* vv      = ws;                 // 409600
    float* xg_f    = vv + 409600;        // 1638400
    float* xgb     = xg_f + 1638400;     // 32768
    float* last_f  = xgb + 32768;        // 8192
    unsigned* hbuf = (unsigned*)(last_f + 8192);   // 8192 u32
    unsigned* cnt  = hbuf + 8192;        // 1 u32 (+pad)
    // total ~8.4 MB

    init_sync<<<1, 64, 0, stream>>>(cnt);
    attn_kernel<<<BVn, 256, 0, stream>>>(codes, mask, tvals, emb_table,
                                         WQ1, WK1, decay, initial, vv);
    xw_kernel<<<dim3(25, 16), 256, 0, stream>>>(vv, w_ih_f, b_ih_f, b_hh_f,
                                                xg_f, BVn);
    xw_kernel<<<dim3(1, 16), 256, 0, stream>>>(vv + 49 * Bb * Ee, w_ih_b,
                                               b_ih_b, b_hh_b, xgb, Bb);
    lstm_persist<<<NB, 256, 0, stream>>>(xg_f, w_hh_f, last_f, hbuf, cnt);
    lstm_tail<<<Bb, 512, 0, stream>>>(last_f, xgb, W_out, b_out, out);
}

// Round 3
// 439.709 us; speedup vs baseline: 2.9623x; 2.1374x over previous
//
#include <hip/hip_runtime.h>
#include <hip/hip_bf16.h>
#include <math.h>

// Problem constants (from reference)
#define Bb 32
#define Vv 50
#define Cc 64
#define Ee 256
#define Aa 128
#define Hh 256
#define Ll 10
#define BVn (Bb*Vv)          // 1600
#define SCALE 0.08838834764831845f   // 1/sqrt(128)

// persistent-LSTM config
#define NB 8          // blocks
#define HS 32         // hidden units per block
#define RWS (4*HS)    // gate rows per block = 128
#define WPAD 264      // bf16 row stride
#define GPAD 132      // f32 row stride for gates scratch
#define CPAD 36       // f32 row stride for c state

// attn LDS strides (bf16 elements)
#define EPAD 264      // emb row stride: 528B, 16B-aligned, 4-bank row step (2-way = free)
#define QPAD 136      // Q/K row stride: 272B, 16B-aligned, 4-bank row step

typedef __bf16 bf16x8 __attribute__((ext_vector_type(8)));
typedef float  f32x4  __attribute__((ext_vector_type(4)));

__device__ __forceinline__ float sigmoidf_(float x) {
    return 1.0f / (1.0f + __expf(-x));
}
__device__ __forceinline__ float tanhf_(float x) {
    return 1.0f - 2.0f / (__expf(2.0f * x) + 1.0f);
}

// ---------------------------------------------------------------------------
// Kernel 0a: decompose WQ1/WK1 into bf16 hi/lo pairs (split-bf16 operands)
// ---------------------------------------------------------------------------
__global__ __launch_bounds__(256) void wsplit(
    const float* __restrict__ wq, const float* __restrict__ wk,
    __bf16* __restrict__ qh, __bf16* __restrict__ ql,
    __bf16* __restrict__ kh, __bf16* __restrict__ kl)
{
    int i = blockIdx.x * 256 + threadIdx.x;    // 0..65535
    if (i < 32768) {
        float f = wq[i];
        __bf16 h = (__bf16)f;
        qh[i] = h; ql[i] = (__bf16)(f - (float)h);
    } else {
        int j = i - 32768;
        float f = wk[j];
        __bf16 h = (__bf16)f;
        kh[j] = h; kl[j] = (__bf16)(f - (float)h);
    }
}

// ---------------------------------------------------------------------------
// Kernel 0b: zero the per-producer sync flags (graph-replay determinism)
// ---------------------------------------------------------------------------
__global__ void init_sync(unsigned* flags) {
    if (threadIdx.x < NB) flags[threadIdx.x] = 0u;
}

// ---------------------------------------------------------------------------
// Kernel 1: attention v2 — split-bf16 MFMA, in-register softmax.
// One block per n=(b,v), 256 threads = 4 waves. LDS ~72 KB -> 2 blocks/CU.
//   phase 1: Q,K = emb @ W^T  (waves split by output column range)
//   phase 2: d = Q K^T, mask, softmax (registers), coef-weighted col-sum
//   phase 3: vv[e] = wsum . emb  (emb re-read from global, L2/L3 resident)
// All MFMA inputs are hi/lo bf16 pairs; 3-term products => ~fp32 accuracy.
// ---------------------------------------------------------------------------
__global__ __launch_bounds__(256, 2) void attn_v2(
    const int*   __restrict__ codes,
    const float* __restrict__ mask,
    const float* __restrict__ tvals,
    const float* __restrict__ emb_table,
    const __bf16* __restrict__ wqhi, const __bf16* __restrict__ wqlo,
    const __bf16* __restrict__ wkhi, const __bf16* __restrict__ wklo,
    const float* __restrict__ decay,
    const float* __restrict__ initial,
    float*       __restrict__ vv)
{
    // one buffer, two lifetimes:
    //  phase 1 reads : ehi[64][EPAD] | elo[64][EPAD]        (33792 elems)
    //  phase 2 reads : qhi|qlo|khi|klo [64][QPAD] each      (34816 elems)
    __shared__ __align__(16) __bf16 buf[4 * Cc * QPAD];
    __shared__ int   codes_l[Cc];
    __shared__ float maskcol_s[Cc], coef_s[Cc], wsum_s[Cc];
    __shared__ float wpart[4][Cc];

    __bf16* ehi = buf;
    __bf16* elo = buf + Cc * EPAD;
    __bf16* qhi = buf;
    __bf16* qlo = buf + 1 * Cc * QPAD;
    __bf16* khi = buf + 2 * Cc * QPAD;
    __bf16* klo = buf + 3 * Cc * QPAD;

    const int n   = blockIdx.x;
    const int tid = threadIdx.x;
    const int b   = n / Vv;
    const int v   = n - b * Vv;
    const int wv  = tid >> 6;          // wave 0..3
    const int lane = tid & 63;
    const int lr  = lane & 15;
    const int lq  = lane >> 4;

    if (tid < Cc) {
        codes_l[tid]   = codes[n * Cc + tid];
        maskcol_s[tid] = mask[n * Cc + tid];
    }
    __syncthreads();

    // gather emb rows, decompose to hi/lo bf16
    for (int i = tid; i < Cc * Ee; i += 256) {
        int c = i >> 8, e = i & 255;
        float f = emb_table[(size_t)codes_l[c] * Ee + e];
        __bf16 h = (__bf16)f;
        ehi[c * EPAD + e] = h;
        elo[c * EPAD + e] = (__bf16)(f - (float)h);
    }
    if (tid < Cc) {
        int code = codes_l[tid];
        float keep = (maskcol_s[tid] == 0.0f) ? 1.0f : 0.0f;
        coef_s[tid] = keep * sigmoidf_(decay[code] * tvals[n] + initial[code]);
    }
    __syncthreads();

    // ---- phase 1: projections. wave -> (Q|K, col half) ----
    const __bf16* bh = (wv < 2) ? wqhi : wkhi;
    const __bf16* bl = (wv < 2) ? wqlo : wklo;
    const int colbase = (wv & 1) * 64;

    f32x4 acc[4][4] = {};
    for (int kt = 0; kt < 8; ++kt) {
        const int k0 = kt * 32 + lq * 8;
        bf16x8 Ahh[4], All[4], Bhh[4], Bll[4];
#pragma unroll
        for (int mf = 0; mf < 4; ++mf) {
            Ahh[mf] = *(const bf16x8*)&ehi[(mf * 16 + lr) * EPAD + k0];
            All[mf] = *(const bf16x8*)&elo[(mf * 16 + lr) * EPAD + k0];
        }
#pragma unroll
        for (int nf = 0; nf < 4; ++nf) {
            const int row = colbase + nf * 16 + lr;
            Bhh[nf] = *(const bf16x8*)&bh[row * Ee + k0];
            Bll[nf] = *(const bf16x8*)&bl[row * Ee + k0];
        }
#pragma unroll
        for (int mf = 0; mf < 4; ++mf)
#pragma unroll
            for (int nf = 0; nf < 4; ++nf) {
                acc[mf][nf] = __builtin_amdgcn_mfma_f32_16x16x32_bf16(Ahh[mf], Bhh[nf], acc[mf][nf], 0, 0, 0);
                acc[mf][nf] = __builtin_amdgcn_mfma_f32_16x16x32_bf16(Ahh[mf], Bll[nf], acc[mf][nf], 0, 0, 0);
                acc[mf][nf] = __builtin_amdgcn_mfma_f32_16x16x32_bf16(All[mf], Bhh[nf], acc[mf][nf], 0, 0, 0);
            }
    }
    __syncthreads();   // done reading ehi/elo; buf becomes Q/K storage

    // store Q/K as hi/lo (C layout: row=(lane>>4)*4+reg, col=lane&15)
    {
        __bf16* dh = (wv < 2) ? qhi : khi;
        __bf16* dl = (wv < 2) ? qlo : klo;
#pragma unroll
        for (int mf = 0; mf < 4; ++mf)
#pragma unroll
            for (int nf = 0; nf < 4; ++nf) {
                const int colb = colbase + nf * 16 + lr;
#pragma unroll
                for (int r = 0; r < 4; ++r) {
                    const int m = mf * 16 + lq * 4 + r;
                    float q = acc[mf][nf][r];
                    __bf16 h = (__bf16)q;
                    dh[m * QPAD + colb] = h;
                    dl[m * QPAD + colb] = (__bf16)(q - (float)h);
                }
            }
    }
    __syncthreads();

    // ---- phase 2: d = Q K^T (wave wv owns rows 16wv..16wv+15, all 64 cols) ----
    f32x4 dacc[4] = {};
    for (int kt = 0; kt < 4; ++kt) {
        const int k0 = kt * 32 + lq * 8;
        bf16x8 Ahh = *(const bf16x8*)&qhi[(wv * 16 + lr) * QPAD + k0];
        bf16x8 All = *(const bf16x8*)&qlo[(wv * 16 + lr) * QPAD + k0];
#pragma unroll
        for (int nf = 0; nf < 4; ++nf) {
            bf16x8 Bhh = *(const bf16x8*)&khi[(nf * 16 + lr) * QPAD + k0];
            bf16x8 Bll = *(const bf16x8*)&klo[(nf * 16 + lr) * QPAD + k0];
            dacc[nf] = __builtin_amdgcn_mfma_f32_16x16x32_bf16(Ahh, Bhh, dacc[nf], 0, 0, 0);
            dacc[nf] = __builtin_amdgcn_mfma_f32_16x16x32_bf16(Ahh, Bll, dacc[nf], 0, 0, 0);
            dacc[nf] = __builtin_amdgcn_mfma_f32_16x16x32_bf16(All, Bhh, dacc[nf], 0, 0, 0);
        }
    }

    // mask + scale + in-register row softmax.
    // lane holds rows {16wv+lq*4+r} (r=0..3), cols {nf*16+lr}.
    // 16 lanes sharing lq hold a row's 64 cols -> reduce via xor 1,2,4,8.
    float p[4][4], inv[4];
#pragma unroll
    for (int r = 0; r < 4; ++r) {
#pragma unroll
        for (int nf = 0; nf < 4; ++nf)
            p[r][nf] = (dacc[nf][r] - maskcol_s[nf * 16 + lr]) * SCALE;
        float mx = fmaxf(fmaxf(p[r][0], p[r][1]), fmaxf(p[r][2], p[r][3]));
        mx = fmaxf(mx, __shfl_xor(mx, 1));
        mx = fmaxf(mx, __shfl_xor(mx, 2));
        mx = fmaxf(mx, __shfl_xor(mx, 4));
        mx = fmaxf(mx, __shfl_xor(mx, 8));
        float s = 0.f;
#pragma unroll
        for (int nf = 0; nf < 4; ++nf) { p[r][nf] = __expf(p[r][nf] - mx); s += p[r][nf]; }
        s += __shfl_xor(s, 1);
        s += __shfl_xor(s, 2);
        s += __shfl_xor(s, 4);
        s += __shfl_xor(s, 8);
        inv[r] = 1.0f / s;
    }

    // wsum[cd] = sum_c coef[c] * softmax[c][cd]
    float part[4];
#pragma unroll
    for (int nf = 0; nf < 4; ++nf) {
        float a = 0.f;
#pragma unroll
        for (int r = 0; r < 4; ++r) {
            const int row = wv * 16 + lq * 4 + r;
            a = fmaf(coef_s[row] * inv[r], p[r][nf], a);
        }
        part[nf] = a;
    }
#pragma unroll
    for (int nf = 0; nf < 4; ++nf) {
        part[nf] += __shfl_xor(part[nf], 16);
        part[nf] += __shfl_xor(part[nf], 32);
    }
    if (lq == 0)
#pragma unroll
        for (int nf = 0; nf < 4; ++nf) wpart[wv][nf * 16 + lr] = part[nf];
    __syncthreads();
    if (tid < Cc)
        wsum_s[tid] = wpart[0][tid] + wpart[1][tid] + wpart[2][tid] + wpart[3][tid];
    __syncthreads();

    // ---- phase 3: vv[e] = sum_d wsum[d] * emb[d][e] (emb from L2/L3) ----
    float a3 = 0.f;
#pragma unroll 8
    for (int d = 0; d < Cc; ++d)
        a3 = fmaf(wsum_s[d], emb_table[(size_t)codes_l[d] * Ee + tid], a3);
    vv[(v * Bb + b) * Ee + tid] = a3;
}

// ---------------------------------------------------------------------------
// Kernel 2: C[m][j] = dot(A[m,:256], W[j,:256]) + b1[j] + b2[j]
// ---------------------------------------------------------------------------
__global__ __launch_bounds__(256) void xw_kernel(
    const float* __restrict__ A, const float* __restrict__ W,
    const float* __restrict__ b1, const float* __restrict__ b2,
    float* __restrict__ Cout, int M)
{
    __shared__ float a_s[64 * 65];
    __shared__ float w_s[64 * 65];
    const int m0 = blockIdx.x * 64, j0 = blockIdx.y * 64;
    const int tid = threadIdx.x, tx = tid & 15, ty = tid >> 4;
    float acc[4][4] = {};
    for (int kc = 0; kc < 256; kc += 64) {
        __syncthreads();
        for (int idx = tid; idx < 4096; idx += 256) {
            int r = idx >> 6, kk = idx & 63;
            int m = m0 + r;
            a_s[r * 65 + kk] = (m < M) ? A[m * 256 + kc + kk] : 0.f;
            w_s[r * 65 + kk] = W[(j0 + r) * 256 + kc + kk];
        }
        __syncthreads();
#pragma unroll 8
        for (int kk = 0; kk < 64; ++kk) {
            float av[4], wv[4];
#pragma unroll
            for (int i = 0; i < 4; ++i) av[i] = a_s[(ty * 4 + i) * 65 + kk];
#pragma unroll
            for (int j = 0; j < 4; ++j) wv[j] = w_s[(tx * 4 + j) * 65 + kk];
#pragma unroll
            for (int i = 0; i < 4; ++i)
#pragma unroll
                for (int j = 0; j < 4; ++j)
                    acc[i][j] = fmaf(av[i], wv[j], acc[i][j]);
        }
    }
#pragma unroll
    for (int i = 0; i < 4; ++i) {
        int m = m0 + ty * 4 + i;
        if (m < M) {
#pragma unroll
            for (int j = 0; j < 4; ++j) {
                int jj = j0 + tx * 4 + j;
                Cout[m * 1024 + jj] = acc[i][j] + b1[jj] + b2[jj];
            }
        }
    }
}

// ---------------------------------------------------------------------------
// Kernel 3: persistent forward-LSTM. 8 blocks x 256 threads.
// Changes vs r2: per-producer epoch flags (no RMW rendezvous), u64 h-exchange,
// xg register prefetch one step ahead.
// ---------------------------------------------------------------------------
__global__ __launch_bounds__(256) void lstm_persist(
    const float* __restrict__ xg,     // [50][32][1024]
    const float* __restrict__ w_hh,   // [1024][256] row-major
    float*       __restrict__ last_f, // [32][256]
    unsigned long long* __restrict__ hbuf,   // [2][32][64] u64 (4xbf16 each)
    unsigned*    __restrict__ flags)  // [NB] epoch flags
{
    __shared__ __align__(16) __bf16 w_s[RWS * WPAD];   // 66 KB
    __shared__ __align__(16) __bf16 h_s[Bb * WPAD];    // 16.5 KB
    __shared__ __align__(16) float  g_s[Bb * GPAD];    // 16.5 KB
    __shared__ __align__(16) float  c_s[Bb * CPAD];    // 4.5 KB

    const int tid = threadIdx.x, blk = blockIdx.x;
    const int hs0 = blk * HS;

    for (int i = tid; i < RWS * Ee; i += 256) {
        int r = i >> 8, k = i & 255;
        int grow = (r >> 5) * Hh + hs0 + (r & 31);
        w_s[r * WPAD + k] = (__bf16)w_hh[grow * Hh + k];
    }
    for (int i = tid; i < Bb * CPAD; i += 256) c_s[i] = 0.f;
    __syncthreads();

    const int l  = tid & 63, wvi = tid >> 6;
    const int lr = l & 15,   lq  = l >> 4;
    const int b_nl = tid >> 3, jg = tid & 7;
    const int col = hs0 + jg * 4;

    // prefetch xg(0)
    const float* x0 = xg + (size_t)b_nl * 1024;
    f32x4 ngi = *(const f32x4*)&x0[0 * Hh + col];
    f32x4 ngf = *(const f32x4*)&x0[1 * Hh + col];
    f32x4 ngg = *(const f32x4*)&x0[2 * Hh + col];
    f32x4 ngo = *(const f32x4*)&x0[3 * Hh + col];

    for (int t = 0; t < Vv; ++t) {
        if (t > 0) {
            // wait for all producers to publish h(t)
            if (tid < NB) {
                int guard = 0;
                while (__hip_atomic_load(&flags[tid], __ATOMIC_ACQUIRE,
                                         __HIP_MEMORY_SCOPE_AGENT) < (unsigned)t &&
                       ++guard < (1 << 27)) {
                    __builtin_amdgcn_s_sleep(1);
                }
            }
            __syncthreads();

            // load h(t) into LDS (u64 = 4 bf16 per load)
            unsigned long long* hb = hbuf + (t & 1) * (Bb * 64);
            unsigned long long* hsu = (unsigned long long*)h_s;
            for (int i = tid; i < Bb * 64; i += 256) {
                int bq = i >> 6, kp = i & 63;
                hsu[bq * (WPAD / 4) + kp] =
                    __hip_atomic_load(hb + i, __ATOMIC_RELAXED, __HIP_MEMORY_SCOPE_AGENT);
            }
            __syncthreads();

            // G[32][128] = h[32][256] @ w_slice^T
            f32x4 a00 = {}, a01 = {}, a10 = {}, a11 = {};
#pragma unroll
            for (int kt = 0; kt < 8; ++kt) {
                int ko = kt * 32 + lq * 8;
                bf16x8 A0 = *(const bf16x8*)&h_s[lr * WPAD + ko];
                bf16x8 A1 = *(const bf16x8*)&h_s[(16 + lr) * WPAD + ko];
                bf16x8 B0 = *(const bf16x8*)&w_s[(wvi * 32 + lr) * WPAD + ko];
                bf16x8 B1 = *(const bf16x8*)&w_s[(wvi * 32 + 16 + lr) * WPAD + ko];
                a00 = __builtin_amdgcn_mfma_f32_16x16x32_bf16(A0, B0, a00, 0, 0, 0);
                a01 = __builtin_amdgcn_mfma_f32_16x16x32_bf16(A0, B1, a01, 0, 0, 0);
                a10 = __builtin_amdgcn_mfma_f32_16x16x32_bf16(A1, B0, a10, 0, 0, 0);
                a11 = __builtin_amdgcn_mfma_f32_16x16x32_bf16(A1, B1, a11, 0, 0, 0);
            }
#pragma unroll
            for (int r = 0; r < 4; ++r) {
                int b0 = lq * 4 + r;
                g_s[b0 * GPAD + wvi * 32 + lr]             = a00[r];
                g_s[b0 * GPAD + wvi * 32 + 16 + lr]        = a01[r];
                g_s[(16 + b0) * GPAD + wvi * 32 + lr]      = a10[r];
                g_s[(16 + b0) * GPAD + wvi * 32 + 16 + lr] = a11[r];
            }
            __syncthreads();
        }

        // nonlinearity (uses prefetched xg(t)); issue prefetch for t+1
        {
            f32x4 gi = ngi, gf = ngf, gg = ngg, go = ngo;
            if (t + 1 < Vv) {
                const float* nx = xg + ((size_t)(t + 1) * Bb + b_nl) * 1024;
                ngi = *(const f32x4*)&nx[0 * Hh + col];
                ngf = *(const f32x4*)&nx[1 * Hh + col];
                ngg = *(const f32x4*)&nx[2 * Hh + col];
                ngo = *(const f32x4*)&nx[3 * Hh + col];
            }
            if (t > 0) {
                int gb = b_nl * GPAD + jg * 4;
                gi += *(const f32x4*)&g_s[gb + 0 * HS];
                gf += *(const f32x4*)&g_s[gb + 1 * HS];
                gg += *(const f32x4*)&g_s[gb + 2 * HS];
                go += *(const f32x4*)&g_s[gb + 3 * HS];
            }
            f32x4 cv = *(const f32x4*)&c_s[b_nl * CPAD + jg * 4];
            float hnew[4];
#pragma unroll
            for (int u = 0; u < 4; ++u) {
                float iv = sigmoidf_(gi[u]);
                float fv = sigmoidf_(gf[u]);
                float gv = tanhf_(gg[u]);
                float ov = sigmoidf_(go[u]);
                float cn = fv * cv[u] + iv * gv;
                cv[u] = cn;
                hnew[u] = ov * tanhf_(cn);
            }
            *(f32x4*)&c_s[b_nl * CPAD + jg * 4] = cv;

            if (t < Vv - 1) {
                unsigned u0 =
                    ((unsigned)__builtin_bit_cast(unsigned short, (__bf16)hnew[0])) |
                    ((unsigned)__builtin_bit_cast(unsigned short, (__bf16)hnew[1]) << 16);
                unsigned u1 =
                    ((unsigned)__builtin_bit_cast(unsigned short, (__bf16)hnew[2])) |
                    ((unsigned)__builtin_bit_cast(unsigned short, (__bf16)hnew[3]) << 16);
                unsigned long long hv = (unsigned long long)u0 |
                                        ((unsigned long long)u1 << 32);
                int base = b_nl * 64 + blk * 8 + jg;
                __hip_atomic_store(hbuf + ((t + 1) & 1) * (Bb * 64) + base, hv,
                                   __ATOMIC_RELAXED, __HIP_MEMORY_SCOPE_AGENT);
            } else {
                f32x4 hv = {hnew[0], hnew[1], hnew[2], hnew[3]};
                *(f32x4*)&last_f[b_nl * Hh + hs0 + jg * 4] = hv;
            }
        }

        if (t < Vv - 1) {
            __syncthreads();
            if (tid == 0) {
                __threadfence();
                __hip_atomic_store(&flags[blk], (unsigned)(t + 1),
                                   __ATOMIC_RELEASE, __HIP_MEMORY_SCOPE_AGENT);
            }
        }
    }
}

// ---------------------------------------------------------------------------
// Kernel 4: tail — backward single cell + head + softmax.
// ---------------------------------------------------------------------------
__global__ __launch_bounds__(512) void lstm_tail(
    const float* __restrict__ last_f,
    const float* __restrict__ xgb,
    const float* __restrict__ W_out,
    const float* __restrict__ b_out,
    float*       __restrict__ out)
{
    __shared__ float last_s[2 * Hh];
    __shared__ float logits_s[Ll];
    const int b = blockIdx.x, tid = threadIdx.x;

    if (tid < Hh) {
        last_s[tid] = last_f[b * Hh + tid];
    } else {
        int j = tid - Hh;
        float ig = sigmoidf_(xgb[b * 1024 + j]);
        float gg = tanhf_(xgb[b * 1024 + 2 * Hh + j]);
        float og = sigmoidf_(xgb[b * 1024 + 3 * Hh + j]);
        last_s[Hh + j] = og * tanhf_(ig * gg);
    }
    __syncthreads();

    if (tid < Ll) {
        float acc = b_out[tid];
        for (int q = 0; q < 2 * Hh; ++q)
            acc = fmaf(last_s[q], W_out[tid * 2 * Hh + q], acc);
        logits_s[tid] = acc;
    }
    __syncthreads();
    if (tid == 0) {
        float mx = -3.0e38f;
        for (int i = 0; i < Ll; ++i) mx = fmaxf(mx, logits_s[i]);
        float ex[Ll], s = 0.f;
        for (int i = 0; i < Ll; ++i) { ex[i] = __expf(logits_s[i] - mx); s += ex[i]; }
        float inv = 1.0f / s;
        for (int i = 0; i < Ll; ++i) out[b * Ll + i] = ex[i] * inv;
    }
}

// ---------------------------------------------------------------------------
extern "C" void kernel_launch(void* const* d_in, const int* in_sizes, int n_in,
                              void* d_out, int out_size, void* d_ws, size_t ws_size,
                              hipStream_t stream) {
    const int*   codes     = (const int*)  d_in[0];
    const float* mask      = (const float*)d_in[1];
    const float* tvals     = (const float*)d_in[2];
    const float* emb_table = (const float*)d_in[4];
    const float* WQ1       = (const float*)d_in[5];
    const float* WK1       = (const float*)d_in[6];
    const float* decay     = (const float*)d_in[7];
    const float* initial   = (const float*)d_in[8];
    const float* w_ih_f    = (const float*)d_in[9];
    const float* w_hh_f    = (const float*)d_in[10];
    const float* b_ih_f    = (const float*)d_in[11];
    const float* b_hh_f    = (const float*)d_in[12];
    const float* w_ih_b    = (const float*)d_in[13];
    // d_in[14] = w_hh_b: unused (backward output = first scan step, h0=c0=0)
    const float* b_ih_b    = (const float*)d_in[15];
    const float* b_hh_b    = (const float*)d_in[16];
    const float* W_out     = (const float*)d_in[17];
    const float* b_out     = (const float*)d_in[18];
    float* out = (float*)d_out;

    // workspace layout
    float* ws      = (float*)d_ws;
    float* vv      = ws;                 // 409600 f
    float* xg_f    = vv + 409600;        // 1638400 f
    float* xgb     = xg_f + 1638400;     // 32768 f
    float* last_f  = xgb + 32768;        // 8192 f
    __bf16* wqhi   = (__bf16*)(last_f + 8192);  // 32768 bf16 each:
    __bf16* wqlo   = wqhi + 32768;
    __bf16* wkhi   = wqlo + 32768;
    __bf16* wklo   = wkhi + 32768;
    unsigned long long* hbuf = (unsigned long long*)(wklo + 32768); // 4096 u64
    unsigned* flags = (unsigned*)(hbuf + 4096);                     // 8 u32
    // total ~8.65 MB

    init_sync<<<1, 64, 0, stream>>>(flags);
    wsplit<<<256, 256, 0, stream>>>(WQ1, WK1, wqhi, wqlo, wkhi, wklo);
    attn_v2<<<BVn, 256, 0, stream>>>(codes, mask, tvals, emb_table,
                                     wqhi, wqlo, wkhi, wklo,
                                     decay, initial, vv);
    xw_kernel<<<dim3(25, 16), 256, 0, stream>>>(vv, w_ih_f, b_ih_f, b_hh_f,
                                                xg_f, BVn);
    xw_kernel<<<dim3(1, 16), 256, 0, stream>>>(vv + 49 * Bb * Ee, w_ih_b,
                                               b_ih_b, b_hh_b, xgb, Bb);
    lstm_persist<<<NB, 256, 0, stream>>>(xg_f, w_hh_f, last_f, hbuf, flags);
    lstm_tail<<<Bb, 512, 0, stream>>>(last_f, xgb, W_out, b_out, out);
}

// Round 4
// 432.580 us; speedup vs baseline: 3.0111x; 1.0165x over previous
//
#include <hip/hip_runtime.h>
#include <hip/hip_bf16.h>
#include <math.h>

// Problem constants (from reference)
#define Bb 32
#define Vv 50
#define Cc 64
#define Ee 256
#define Aa 128
#define Hh 256
#define Ll 10
#define BVn (Bb*Vv)          // 1600
#define SCALE 0.08838834764831845f   // 1/sqrt(128)

// persistent-LSTM config
#define NB 8          // blocks
#define HS 32         // hidden units per block
#define RWS (4*HS)    // gate rows per block = 128
#define WPAD 264      // bf16 row stride
#define GPAD 132      // f32 row stride for gates scratch
#define CPAD 36       // f32 row stride for c state

// attn LDS strides (bf16 elements)
#define EPAD 264
#define QPAD 136

typedef __bf16 bf16x8 __attribute__((ext_vector_type(8)));
typedef float  f32x4  __attribute__((ext_vector_type(4)));

__device__ __forceinline__ float sigmoidf_(float x) {
    return 1.0f / (1.0f + __expf(-x));
}
__device__ __forceinline__ float tanhf_(float x) {
    return 1.0f - 2.0f / (__expf(2.0f * x) + 1.0f);
}

// ---------------------------------------------------------------------------
// Kernel 0: decompose WQ1/WK1 into bf16 hi/lo pairs; block 0 zeroes sync flags
// ---------------------------------------------------------------------------
__global__ __launch_bounds__(256) void wsplit(
    const float* __restrict__ wq, const float* __restrict__ wk,
    __bf16* __restrict__ qh, __bf16* __restrict__ ql,
    __bf16* __restrict__ kh, __bf16* __restrict__ kl,
    unsigned* __restrict__ flags)
{
    if (blockIdx.x == 0 && threadIdx.x < NB)
        __hip_atomic_store(&flags[threadIdx.x], 0u, __ATOMIC_RELAXED,
                           __HIP_MEMORY_SCOPE_AGENT);
    int i = blockIdx.x * 256 + threadIdx.x;    // 0..65535
    if (i < 32768) {
        float f = wq[i];
        __bf16 h = (__bf16)f;
        qh[i] = h; ql[i] = (__bf16)(f - (float)h);
    } else {
        int j = i - 32768;
        float f = wk[j];
        __bf16 h = (__bf16)f;
        kh[j] = h; kl[j] = (__bf16)(f - (float)h);
    }
}

// ---------------------------------------------------------------------------
// Kernel 1: attention — split-bf16 MFMA, in-register softmax. (unchanged r3)
// ---------------------------------------------------------------------------
__global__ __launch_bounds__(256, 2) void attn_v2(
    const int*   __restrict__ codes,
    const float* __restrict__ mask,
    const float* __restrict__ tvals,
    const float* __restrict__ emb_table,
    const __bf16* __restrict__ wqhi, const __bf16* __restrict__ wqlo,
    const __bf16* __restrict__ wkhi, const __bf16* __restrict__ wklo,
    const float* __restrict__ decay,
    const float* __restrict__ initial,
    float*       __restrict__ vv)
{
    __shared__ __align__(16) __bf16 buf[4 * Cc * QPAD];
    __shared__ int   codes_l[Cc];
    __shared__ float maskcol_s[Cc], coef_s[Cc], wsum_s[Cc];
    __shared__ float wpart[4][Cc];

    __bf16* ehi = buf;
    __bf16* elo = buf + Cc * EPAD;
    __bf16* qhi = buf;
    __bf16* qlo = buf + 1 * Cc * QPAD;
    __bf16* khi = buf + 2 * Cc * QPAD;
    __bf16* klo = buf + 3 * Cc * QPAD;

    const int n   = blockIdx.x;
    const int tid = threadIdx.x;
    const int b   = n / Vv;
    const int v   = n - b * Vv;
    const int wv  = tid >> 6;
    const int lane = tid & 63;
    const int lr  = lane & 15;
    const int lq  = lane >> 4;

    if (tid < Cc) {
        codes_l[tid]   = codes[n * Cc + tid];
        maskcol_s[tid] = mask[n * Cc + tid];
    }
    __syncthreads();

    for (int i = tid; i < Cc * Ee; i += 256) {
        int c = i >> 8, e = i & 255;
        float f = emb_table[(size_t)codes_l[c] * Ee + e];
        __bf16 h = (__bf16)f;
        ehi[c * EPAD + e] = h;
        elo[c * EPAD + e] = (__bf16)(f - (float)h);
    }
    if (tid < Cc) {
        int code = codes_l[tid];
        float keep = (maskcol_s[tid] == 0.0f) ? 1.0f : 0.0f;
        coef_s[tid] = keep * sigmoidf_(decay[code] * tvals[n] + initial[code]);
    }
    __syncthreads();

    const __bf16* bh = (wv < 2) ? wqhi : wkhi;
    const __bf16* bl = (wv < 2) ? wqlo : wklo;
    const int colbase = (wv & 1) * 64;

    f32x4 acc[4][4] = {};
    for (int kt = 0; kt < 8; ++kt) {
        const int k0 = kt * 32 + lq * 8;
        bf16x8 Ahh[4], All[4], Bhh[4], Bll[4];
#pragma unroll
        for (int mf = 0; mf < 4; ++mf) {
            Ahh[mf] = *(const bf16x8*)&ehi[(mf * 16 + lr) * EPAD + k0];
            All[mf] = *(const bf16x8*)&elo[(mf * 16 + lr) * EPAD + k0];
        }
#pragma unroll
        for (int nf = 0; nf < 4; ++nf) {
            const int row = colbase + nf * 16 + lr;
            Bhh[nf] = *(const bf16x8*)&bh[row * Ee + k0];
            Bll[nf] = *(const bf16x8*)&bl[row * Ee + k0];
        }
#pragma unroll
        for (int mf = 0; mf < 4; ++mf)
#pragma unroll
            for (int nf = 0; nf < 4; ++nf) {
                acc[mf][nf] = __builtin_amdgcn_mfma_f32_16x16x32_bf16(Ahh[mf], Bhh[nf], acc[mf][nf], 0, 0, 0);
                acc[mf][nf] = __builtin_amdgcn_mfma_f32_16x16x32_bf16(Ahh[mf], Bll[nf], acc[mf][nf], 0, 0, 0);
                acc[mf][nf] = __builtin_amdgcn_mfma_f32_16x16x32_bf16(All[mf], Bhh[nf], acc[mf][nf], 0, 0, 0);
            }
    }
    __syncthreads();

    {
        __bf16* dh = (wv < 2) ? qhi : khi;
        __bf16* dl = (wv < 2) ? qlo : klo;
#pragma unroll
        for (int mf = 0; mf < 4; ++mf)
#pragma unroll
            for (int nf = 0; nf < 4; ++nf) {
                const int colb = colbase + nf * 16 + lr;
#pragma unroll
                for (int r = 0; r < 4; ++r) {
                    const int m = mf * 16 + lq * 4 + r;
                    float q = acc[mf][nf][r];
                    __bf16 h = (__bf16)q;
                    dh[m * QPAD + colb] = h;
                    dl[m * QPAD + colb] = (__bf16)(q - (float)h);
                }
            }
    }
    __syncthreads();

    f32x4 dacc[4] = {};
    for (int kt = 0; kt < 4; ++kt) {
        const int k0 = kt * 32 + lq * 8;
        bf16x8 Ahh = *(const bf16x8*)&qhi[(wv * 16 + lr) * QPAD + k0];
        bf16x8 All = *(const bf16x8*)&qlo[(wv * 16 + lr) * QPAD + k0];
#pragma unroll
        for (int nf = 0; nf < 4; ++nf) {
            bf16x8 Bhh = *(const bf16x8*)&khi[(nf * 16 + lr) * QPAD + k0];
            bf16x8 Bll = *(const bf16x8*)&klo[(nf * 16 + lr) * QPAD + k0];
            dacc[nf] = __builtin_amdgcn_mfma_f32_16x16x32_bf16(Ahh, Bhh, dacc[nf], 0, 0, 0);
            dacc[nf] = __builtin_amdgcn_mfma_f32_16x16x32_bf16(Ahh, Bll, dacc[nf], 0, 0, 0);
            dacc[nf] = __builtin_amdgcn_mfma_f32_16x16x32_bf16(All, Bhh, dacc[nf], 0, 0, 0);
        }
    }

    float p[4][4], inv[4];
#pragma unroll
    for (int r = 0; r < 4; ++r) {
#pragma unroll
        for (int nf = 0; nf < 4; ++nf)
            p[r][nf] = (dacc[nf][r] - maskcol_s[nf * 16 + lr]) * SCALE;
        float mx = fmaxf(fmaxf(p[r][0], p[r][1]), fmaxf(p[r][2], p[r][3]));
        mx = fmaxf(mx, __shfl_xor(mx, 1));
        mx = fmaxf(mx, __shfl_xor(mx, 2));
        mx = fmaxf(mx, __shfl_xor(mx, 4));
        mx = fmaxf(mx, __shfl_xor(mx, 8));
        float s = 0.f;
#pragma unroll
        for (int nf = 0; nf < 4; ++nf) { p[r][nf] = __expf(p[r][nf] - mx); s += p[r][nf]; }
        s += __shfl_xor(s, 1);
        s += __shfl_xor(s, 2);
        s += __shfl_xor(s, 4);
        s += __shfl_xor(s, 8);
        inv[r] = 1.0f / s;
    }

    float part[4];
#pragma unroll
    for (int nf = 0; nf < 4; ++nf) {
        float a = 0.f;
#pragma unroll
        for (int r = 0; r < 4; ++r) {
            const int row = wv * 16 + lq * 4 + r;
            a = fmaf(coef_s[row] * inv[r], p[r][nf], a);
        }
        part[nf] = a;
    }
#pragma unroll
    for (int nf = 0; nf < 4; ++nf) {
        part[nf] += __shfl_xor(part[nf], 16);
        part[nf] += __shfl_xor(part[nf], 32);
    }
    if (lq == 0)
#pragma unroll
        for (int nf = 0; nf < 4; ++nf) wpart[wv][nf * 16 + lr] = part[nf];
    __syncthreads();
    if (tid < Cc)
        wsum_s[tid] = wpart[0][tid] + wpart[1][tid] + wpart[2][tid] + wpart[3][tid];
    __syncthreads();

    float a3 = 0.f;
#pragma unroll 8
    for (int d = 0; d < Cc; ++d)
        a3 = fmaf(wsum_s[d], emb_table[(size_t)codes_l[d] * Ee + tid], a3);
    vv[(v * Bb + b) * Ee + tid] = a3;
}

// ---------------------------------------------------------------------------
// Kernel 2: merged fwd+bwd x@W^T. blockIdx.x<25 -> forward; ==25 -> backward.
// ---------------------------------------------------------------------------
__global__ __launch_bounds__(256) void xw_kernel(
    const float* __restrict__ vv,
    const float* __restrict__ w_ih_f, const float* __restrict__ b_ih_f,
    const float* __restrict__ b_hh_f,
    const float* __restrict__ w_ih_b, const float* __restrict__ b_ih_b,
    const float* __restrict__ b_hh_b,
    float* __restrict__ xg_f, float* __restrict__ xgb)
{
    const bool bwd = (blockIdx.x == 25);
    const float* A  = bwd ? (vv + 49 * Bb * Ee) : vv;
    const float* W  = bwd ? w_ih_b : w_ih_f;
    const float* b1 = bwd ? b_ih_b : b_ih_f;
    const float* b2 = bwd ? b_hh_b : b_hh_f;
    float* Cout     = bwd ? xgb : xg_f;
    const int M     = bwd ? Bb : BVn;
    const int m0    = bwd ? 0 : blockIdx.x * 64;
    const int j0    = blockIdx.y * 64;

    __shared__ float a_s[64 * 65];
    __shared__ float w_s[64 * 65];
    const int tid = threadIdx.x, tx = tid & 15, ty = tid >> 4;
    float acc[4][4] = {};
    for (int kc = 0; kc < 256; kc += 64) {
        __syncthreads();
        for (int idx = tid; idx < 4096; idx += 256) {
            int r = idx >> 6, kk = idx & 63;
            int m = m0 + r;
            a_s[r * 65 + kk] = (m < M) ? A[m * 256 + kc + kk] : 0.f;
            w_s[r * 65 + kk] = W[(j0 + r) * 256 + kc + kk];
        }
        __syncthreads();
#pragma unroll 8
        for (int kk = 0; kk < 64; ++kk) {
            float av[4], wv[4];
#pragma unroll
            for (int i = 0; i < 4; ++i) av[i] = a_s[(ty * 4 + i) * 65 + kk];
#pragma unroll
            for (int j = 0; j < 4; ++j) wv[j] = w_s[(tx * 4 + j) * 65 + kk];
#pragma unroll
            for (int i = 0; i < 4; ++i)
#pragma unroll
                for (int j = 0; j < 4; ++j)
                    acc[i][j] = fmaf(av[i], wv[j], acc[i][j]);
        }
    }
#pragma unroll
    for (int i = 0; i < 4; ++i) {
        int m = m0 + ty * 4 + i;
        if (m < M) {
#pragma unroll
            for (int j = 0; j < 4; ++j) {
                int jj = j0 + tx * 4 + j;
                Cout[m * 1024 + jj] = acc[i][j] + b1[jj] + b2[jj];
            }
        }
    }
}

// ---------------------------------------------------------------------------
// Kernel 3: persistent forward-LSTM. 8 blocks x 256 threads.
// r4 changes: relaxed spin (no per-poll cache-inv) + single acquire;
// no threadfence; fused per-producer poll+load (8 groups of 32 threads).
// ---------------------------------------------------------------------------
__global__ __launch_bounds__(256) void lstm_persist(
    const float* __restrict__ xg,     // [50][32][1024]
    const float* __restrict__ w_hh,   // [1024][256] row-major
    float*       __restrict__ last_f, // [32][256]
    unsigned long long* __restrict__ hbuf,   // [2][32][64] u64 (4xbf16)
    unsigned*    __restrict__ flags)  // [NB] epoch flags
{
    __shared__ __align__(16) __bf16 w_s[RWS * WPAD];   // 66 KB
    __shared__ __align__(16) __bf16 h_s[Bb * WPAD];    // 16.5 KB
    __shared__ __align__(16) float  g_s[Bb * GPAD];    // 16.5 KB
    __shared__ __align__(16) float  c_s[Bb * CPAD];    // 4.5 KB

    const int tid = threadIdx.x, blk = blockIdx.x;
    const int hs0 = blk * HS;

    for (int i = tid; i < RWS * Ee; i += 256) {
        int r = i >> 8, k = i & 255;
        int grow = (r >> 5) * Hh + hs0 + (r & 31);
        w_s[r * WPAD + k] = (__bf16)w_hh[grow * Hh + k];
    }
    for (int i = tid; i < Bb * CPAD; i += 256) c_s[i] = 0.f;
    __syncthreads();

    const int l  = tid & 63, wvi = tid >> 6;
    const int lr = l & 15,   lq  = l >> 4;
    const int b_nl = tid >> 3, jg = tid & 7;
    const int col = hs0 + jg * 4;
    const int pg = tid >> 5, pj = tid & 31;   // poll group / lane-in-group

    // prefetch xg(0)
    const float* x0 = xg + (size_t)b_nl * 1024;
    f32x4 ngi = *(const f32x4*)&x0[0 * Hh + col];
    f32x4 ngf = *(const f32x4*)&x0[1 * Hh + col];
    f32x4 ngg = *(const f32x4*)&x0[2 * Hh + col];
    f32x4 ngo = *(const f32x4*)&x0[3 * Hh + col];

    for (int t = 0; t < Vv; ++t) {
        if (t > 0) {
            // ---- group pg waits for producer pg (relaxed spin, cheap) ----
            {
                int guard = 0;
                while (__hip_atomic_load(&flags[pg], __ATOMIC_RELAXED,
                                         __HIP_MEMORY_SCOPE_AGENT) < (unsigned)t &&
                       ++guard < (1 << 27)) {
                    __builtin_amdgcn_s_sleep(1);
                }
                // one acquire for ordering (≈1 iteration)
                guard = 0;
                while (__hip_atomic_load(&flags[pg], __ATOMIC_ACQUIRE,
                                         __HIP_MEMORY_SCOPE_AGENT) < (unsigned)t &&
                       ++guard < (1 << 27)) {
                    __builtin_amdgcn_s_sleep(1);
                }
                asm volatile("" ::: "memory");
            }
            // ---- load producer pg's h chunk (8 u64 per thread) ----
            {
                unsigned long long* hb = hbuf + (t & 1) * (Bb * 64);
                unsigned long long* hsu = (unsigned long long*)h_s;
#pragma unroll
                for (int q = 0; q < 8; ++q) {
                    int u = pj + 32 * q;            // 0..255 in chunk
                    int batch = u >> 3, col8 = u & 7;
                    hsu[batch * (WPAD / 4) + pg * 8 + col8] =
                        __hip_atomic_load(hb + batch * 64 + pg * 8 + col8,
                                          __ATOMIC_RELAXED, __HIP_MEMORY_SCOPE_AGENT);
                }
            }
            __syncthreads();

            // ---- G[32][128] = h[32][256] @ w_slice^T ----
            f32x4 a00 = {}, a01 = {}, a10 = {}, a11 = {};
#pragma unroll
            for (int kt = 0; kt < 8; ++kt) {
                int ko = kt * 32 + lq * 8;
                bf16x8 A0 = *(const bf16x8*)&h_s[lr * WPAD + ko];
                bf16x8 A1 = *(const bf16x8*)&h_s[(16 + lr) * WPAD + ko];
                bf16x8 B0 = *(const bf16x8*)&w_s[(wvi * 32 + lr) * WPAD + ko];
                bf16x8 B1 = *(const bf16x8*)&w_s[(wvi * 32 + 16 + lr) * WPAD + ko];
                a00 = __builtin_amdgcn_mfma_f32_16x16x32_bf16(A0, B0, a00, 0, 0, 0);
                a01 = __builtin_amdgcn_mfma_f32_16x16x32_bf16(A0, B1, a01, 0, 0, 0);
                a10 = __builtin_amdgcn_mfma_f32_16x16x32_bf16(A1, B0, a10, 0, 0, 0);
                a11 = __builtin_amdgcn_mfma_f32_16x16x32_bf16(A1, B1, a11, 0, 0, 0);
            }
#pragma unroll
            for (int r = 0; r < 4; ++r) {
                int b0 = lq * 4 + r;
                g_s[b0 * GPAD + wvi * 32 + lr]             = a00[r];
                g_s[b0 * GPAD + wvi * 32 + 16 + lr]        = a01[r];
                g_s[(16 + b0) * GPAD + wvi * 32 + lr]      = a10[r];
                g_s[(16 + b0) * GPAD + wvi * 32 + 16 + lr] = a11[r];
            }
            __syncthreads();
        }

        // ---- nonlinearity (prefetched xg(t)); prefetch t+1 ----
        {
            f32x4 gi = ngi, gf = ngf, gg = ngg, go = ngo;
            if (t + 1 < Vv) {
                const float* nx = xg + ((size_t)(t + 1) * Bb + b_nl) * 1024;
                ngi = *(const f32x4*)&nx[0 * Hh + col];
                ngf = *(const f32x4*)&nx[1 * Hh + col];
                ngg = *(const f32x4*)&nx[2 * Hh + col];
                ngo = *(const f32x4*)&nx[3 * Hh + col];
            }
            if (t > 0) {
                int gb = b_nl * GPAD + jg * 4;
                gi += *(const f32x4*)&g_s[gb + 0 * HS];
                gf += *(const f32x4*)&g_s[gb + 1 * HS];
                gg += *(const f32x4*)&g_s[gb + 2 * HS];
                go += *(const f32x4*)&g_s[gb + 3 * HS];
            }
            f32x4 cv = *(const f32x4*)&c_s[b_nl * CPAD + jg * 4];
            float hnew[4];
#pragma unroll
            for (int u = 0; u < 4; ++u) {
                float iv = sigmoidf_(gi[u]);
                float fv = sigmoidf_(gf[u]);
                float gv = tanhf_(gg[u]);
                float ov = sigmoidf_(go[u]);
                float cn = fv * cv[u] + iv * gv;
                cv[u] = cn;
                hnew[u] = ov * tanhf_(cn);
            }
            *(f32x4*)&c_s[b_nl * CPAD + jg * 4] = cv;

            if (t < Vv - 1) {
                unsigned u0 =
                    ((unsigned)__builtin_bit_cast(unsigned short, (__bf16)hnew[0])) |
                    ((unsigned)__builtin_bit_cast(unsigned short, (__bf16)hnew[1]) << 16);
                unsigned u1 =
                    ((unsigned)__builtin_bit_cast(unsigned short, (__bf16)hnew[2])) |
                    ((unsigned)__builtin_bit_cast(unsigned short, (__bf16)hnew[3]) << 16);
                unsigned long long hv = (unsigned long long)u0 |
                                        ((unsigned long long)u1 << 32);
                int base = b_nl * 64 + blk * 8 + jg;
                __hip_atomic_store(hbuf + ((t + 1) & 1) * (Bb * 64) + base, hv,
                                   __ATOMIC_RELAXED, __HIP_MEMORY_SCOPE_AGENT);
            } else {
                f32x4 hv = {hnew[0], hnew[1], hnew[2], hnew[3]};
                *(f32x4*)&last_f[b_nl * Hh + hs0 + jg * 4] = hv;
            }
        }

        if (t < Vv - 1) {
            // barrier drains vmcnt for ALL waves -> h stores are L3-visible
            __syncthreads();
            if (tid == 0) {
                __hip_atomic_store(&flags[blk], (unsigned)(t + 1),
                                   __ATOMIC_RELEASE, __HIP_MEMORY_SCOPE_AGENT);
            }
        }
    }
}

// ---------------------------------------------------------------------------
// Kernel 4: tail — backward single cell + head + softmax.
// ---------------------------------------------------------------------------
__global__ __launch_bounds__(512) void lstm_tail(
    const float* __restrict__ last_f,
    const float* __restrict__ xgb,
    const float* __restrict__ W_out,
    const float* __restrict__ b_out,
    float*       __restrict__ out)
{
    __shared__ float last_s[2 * Hh];
    __shared__ float logits_s[Ll];
    const int b = blockIdx.x, tid = threadIdx.x;

    if (tid < Hh) {
        last_s[tid] = last_f[b * Hh + tid];
    } else {
        int j = tid - Hh;
        float ig = sigmoidf_(xgb[b * 1024 + j]);
        float gg = tanhf_(xgb[b * 1024 + 2 * Hh + j]);
        float og = sigmoidf_(xgb[b * 1024 + 3 * Hh + j]);
        last_s[Hh + j] = og * tanhf_(ig * gg);
    }
    __syncthreads();

    if (tid < Ll) {
        float acc = b_out[tid];
        for (int q = 0; q < 2 * Hh; ++q)
            acc = fmaf(last_s[q], W_out[tid * 2 * Hh + q], acc);
        logits_s[tid] = acc;
    }
    __syncthreads();
    if (tid == 0) {
        float mx = -3.0e38f;
        for (int i = 0; i < Ll; ++i) mx = fmaxf(mx, logits_s[i]);
        float ex[Ll], s = 0.f;
        for (int i = 0; i < Ll; ++i) { ex[i] = __expf(logits_s[i] - mx); s += ex[i]; }
        float inv = 1.0f / s;
        for (int i = 0; i < Ll; ++i) out[b * Ll + i] = ex[i] * inv;
    }
}

// ---------------------------------------------------------------------------
extern "C" void kernel_launch(void* const* d_in, const int* in_sizes, int n_in,
                              void* d_out, int out_size, void* d_ws, size_t ws_size,
                              hipStream_t stream) {
    const int*   codes     = (const int*)  d_in[0];
    const float* mask      = (const float*)d_in[1];
    const float* tvals     = (const float*)d_in[2];
    const float* emb_table = (const float*)d_in[4];
    const float* WQ1       = (const float*)d_in[5];
    const float* WK1       = (const float*)d_in[6];
    const float* decay     = (const float*)d_in[7];
    const float* initial   = (const float*)d_in[8];
    const float* w_ih_f    = (const float*)d_in[9];
    const float* w_hh_f    = (const float*)d_in[10];
    const float* b_ih_f    = (const float*)d_in[11];
    const float* b_hh_f    = (const float*)d_in[12];
    const float* w_ih_b    = (const float*)d_in[13];
    // d_in[14] = w_hh_b: unused (backward output = first scan step, h0=c0=0)
    const float* b_ih_b    = (const float*)d_in[15];
    const float* b_hh_b    = (const float*)d_in[16];
    const float* W_out     = (const float*)d_in[17];
    const float* b_out     = (const float*)d_in[18];
    float* out = (float*)d_out;

    // workspace layout
    float* ws      = (float*)d_ws;
    float* vv      = ws;                 // 409600 f
    float* xg_f    = vv + 409600;        // 1638400 f
    float* xgb     = xg_f + 1638400;     // 32768 f
    float* last_f  = xgb + 32768;        // 8192 f
    __bf16* wqhi   = (__bf16*)(last_f + 8192);
    __bf16* wqlo   = wqhi + 32768;
    __bf16* wkhi   = wqlo + 32768;
    __bf16* wklo   = wkhi + 32768;
    unsigned long long* hbuf = (unsigned long long*)(wklo + 32768); // 4096 u64
    unsigned* flags = (unsigned*)(hbuf + 4096);                     // 8 u32

    wsplit<<<256, 256, 0, stream>>>(WQ1, WK1, wqhi, wqlo, wkhi, wklo, flags);
    attn_v2<<<BVn, 256, 0, stream>>>(codes, mask, tvals, emb_table,
                                     wqhi, wqlo, wkhi, wklo,
                                     decay, initial, vv);
    xw_kernel<<<dim3(26, 16), 256, 0, stream>>>(vv, w_ih_f, b_ih_f, b_hh_f,
                                                w_ih_b, b_ih_b, b_hh_b,
                                                xg_f, xgb);
    lstm_persist<<<NB, 256, 0, stream>>>(xg_f, w_hh_f, last_f, hbuf, flags);
    lstm_tail<<<Bb, 512, 0, stream>>>(last_f, xgb, W_out, b_out, out);
}

// Round 5
// 346.208 us; speedup vs baseline: 3.7623x; 1.2495x over previous
//
#include <hip/hip_runtime.h>
#include <hip/hip_bf16.h>
#include <math.h>

// Problem constants (from reference)
#define Bb 32
#define Vv 50
#define Cc 64
#define Ee 256
#define Aa 128
#define Hh 256
#define Ll 10
#define BVn (Bb*Vv)          // 1600
#define SCALE 0.08838834764831845f   // 1/sqrt(128)

// persistent-LSTM config
#define NB 8          // blocks
#define HS 32         // hidden units per block
#define RWS (4*HS)    // gate rows per block = 128
#define WPAD 264      // bf16 row stride
#define GPAD 132      // f32 row stride for gates scratch
#define CPAD 36       // f32 row stride for c state
#define FSTR 64       // flag stride in u32 (256 B -> one cache line per flag)

// attn LDS strides (bf16 elements)
#define EPAD 264
#define QPAD 136

typedef __bf16 bf16x8 __attribute__((ext_vector_type(8)));
typedef float  f32x4  __attribute__((ext_vector_type(4)));

__device__ __forceinline__ float sigmoidf_(float x) {
    return 1.0f / (1.0f + __expf(-x));
}
__device__ __forceinline__ float tanhf_(float x) {
    return 1.0f - 2.0f / (__expf(2.0f * x) + 1.0f);
}

// ---------------------------------------------------------------------------
// Kernel 0: decompose WQ1/WK1 into bf16 hi/lo pairs; block 0 zeroes sync flags
// ---------------------------------------------------------------------------
__global__ __launch_bounds__(256) void wsplit(
    const float* __restrict__ wq, const float* __restrict__ wk,
    __bf16* __restrict__ qh, __bf16* __restrict__ ql,
    __bf16* __restrict__ kh, __bf16* __restrict__ kl,
    unsigned* __restrict__ flags)
{
    if (blockIdx.x == 0) {
        for (int i = threadIdx.x; i < NB * FSTR; i += 256)
            __hip_atomic_store(&flags[i], 0u, __ATOMIC_RELAXED,
                               __HIP_MEMORY_SCOPE_AGENT);
    }
    int i = blockIdx.x * 256 + threadIdx.x;    // 0..65535
    if (i < 32768) {
        float f = wq[i];
        __bf16 h = (__bf16)f;
        qh[i] = h; ql[i] = (__bf16)(f - (float)h);
    } else {
        int j = i - 32768;
        float f = wk[j];
        __bf16 h = (__bf16)f;
        kh[j] = h; kl[j] = (__bf16)(f - (float)h);
    }
}

// ---------------------------------------------------------------------------
// Kernel 1: attention — split-bf16 MFMA, in-register softmax. (unchanged)
// ---------------------------------------------------------------------------
__global__ __launch_bounds__(256, 2) void attn_v2(
    const int*   __restrict__ codes,
    const float* __restrict__ mask,
    const float* __restrict__ tvals,
    const float* __restrict__ emb_table,
    const __bf16* __restrict__ wqhi, const __bf16* __restrict__ wqlo,
    const __bf16* __restrict__ wkhi, const __bf16* __restrict__ wklo,
    const float* __restrict__ decay,
    const float* __restrict__ initial,
    float*       __restrict__ vv)
{
    __shared__ __align__(16) __bf16 buf[4 * Cc * QPAD];
    __shared__ int   codes_l[Cc];
    __shared__ float maskcol_s[Cc], coef_s[Cc], wsum_s[Cc];
    __shared__ float wpart[4][Cc];

    __bf16* ehi = buf;
    __bf16* elo = buf + Cc * EPAD;
    __bf16* qhi = buf;
    __bf16* qlo = buf + 1 * Cc * QPAD;
    __bf16* khi = buf + 2 * Cc * QPAD;
    __bf16* klo = buf + 3 * Cc * QPAD;

    const int n   = blockIdx.x;
    const int tid = threadIdx.x;
    const int b   = n / Vv;
    const int v   = n - b * Vv;
    const int wv  = tid >> 6;
    const int lane = tid & 63;
    const int lr  = lane & 15;
    const int lq  = lane >> 4;

    if (tid < Cc) {
        codes_l[tid]   = codes[n * Cc + tid];
        maskcol_s[tid] = mask[n * Cc + tid];
    }
    __syncthreads();

    for (int i = tid; i < Cc * Ee; i += 256) {
        int c = i >> 8, e = i & 255;
        float f = emb_table[(size_t)codes_l[c] * Ee + e];
        __bf16 h = (__bf16)f;
        ehi[c * EPAD + e] = h;
        elo[c * EPAD + e] = (__bf16)(f - (float)h);
    }
    if (tid < Cc) {
        int code = codes_l[tid];
        float keep = (maskcol_s[tid] == 0.0f) ? 1.0f : 0.0f;
        coef_s[tid] = keep * sigmoidf_(decay[code] * tvals[n] + initial[code]);
    }
    __syncthreads();

    const __bf16* bh = (wv < 2) ? wqhi : wkhi;
    const __bf16* bl = (wv < 2) ? wqlo : wklo;
    const int colbase = (wv & 1) * 64;

    f32x4 acc[4][4] = {};
    for (int kt = 0; kt < 8; ++kt) {
        const int k0 = kt * 32 + lq * 8;
        bf16x8 Ahh[4], All[4], Bhh[4], Bll[4];
#pragma unroll
        for (int mf = 0; mf < 4; ++mf) {
            Ahh[mf] = *(const bf16x8*)&ehi[(mf * 16 + lr) * EPAD + k0];
            All[mf] = *(const bf16x8*)&elo[(mf * 16 + lr) * EPAD + k0];
        }
#pragma unroll
        for (int nf = 0; nf < 4; ++nf) {
            const int row = colbase + nf * 16 + lr;
            Bhh[nf] = *(const bf16x8*)&bh[row * Ee + k0];
            Bll[nf] = *(const bf16x8*)&bl[row * Ee + k0];
        }
#pragma unroll
        for (int mf = 0; mf < 4; ++mf)
#pragma unroll
            for (int nf = 0; nf < 4; ++nf) {
                acc[mf][nf] = __builtin_amdgcn_mfma_f32_16x16x32_bf16(Ahh[mf], Bhh[nf], acc[mf][nf], 0, 0, 0);
                acc[mf][nf] = __builtin_amdgcn_mfma_f32_16x16x32_bf16(Ahh[mf], Bll[nf], acc[mf][nf], 0, 0, 0);
                acc[mf][nf] = __builtin_amdgcn_mfma_f32_16x16x32_bf16(All[mf], Bhh[nf], acc[mf][nf], 0, 0, 0);
            }
    }
    __syncthreads();

    {
        __bf16* dh = (wv < 2) ? qhi : khi;
        __bf16* dl = (wv < 2) ? qlo : klo;
#pragma unroll
        for (int mf = 0; mf < 4; ++mf)
#pragma unroll
            for (int nf = 0; nf < 4; ++nf) {
                const int colb = colbase + nf * 16 + lr;
#pragma unroll
                for (int r = 0; r < 4; ++r) {
                    const int m = mf * 16 + lq * 4 + r;
                    float q = acc[mf][nf][r];
                    __bf16 h = (__bf16)q;
                    dh[m * QPAD + colb] = h;
                    dl[m * QPAD + colb] = (__bf16)(q - (float)h);
                }
            }
    }
    __syncthreads();

    f32x4 dacc[4] = {};
    for (int kt = 0; kt < 4; ++kt) {
        const int k0 = kt * 32 + lq * 8;
        bf16x8 Ahh = *(const bf16x8*)&qhi[(wv * 16 + lr) * QPAD + k0];
        bf16x8 All = *(const bf16x8*)&qlo[(wv * 16 + lr) * QPAD + k0];
#pragma unroll
        for (int nf = 0; nf < 4; ++nf) {
            bf16x8 Bhh = *(const bf16x8*)&khi[(nf * 16 + lr) * QPAD + k0];
            bf16x8 Bll = *(const bf16x8*)&klo[(nf * 16 + lr) * QPAD + k0];
            dacc[nf] = __builtin_amdgcn_mfma_f32_16x16x32_bf16(Ahh, Bhh, dacc[nf], 0, 0, 0);
            dacc[nf] = __builtin_amdgcn_mfma_f32_16x16x32_bf16(Ahh, Bll, dacc[nf], 0, 0, 0);
            dacc[nf] = __builtin_amdgcn_mfma_f32_16x16x32_bf16(All, Bhh, dacc[nf], 0, 0, 0);
        }
    }

    float p[4][4], inv[4];
#pragma unroll
    for (int r = 0; r < 4; ++r) {
#pragma unroll
        for (int nf = 0; nf < 4; ++nf)
            p[r][nf] = (dacc[nf][r] - maskcol_s[nf * 16 + lr]) * SCALE;
        float mx = fmaxf(fmaxf(p[r][0], p[r][1]), fmaxf(p[r][2], p[r][3]));
        mx = fmaxf(mx, __shfl_xor(mx, 1));
        mx = fmaxf(mx, __shfl_xor(mx, 2));
        mx = fmaxf(mx, __shfl_xor(mx, 4));
        mx = fmaxf(mx, __shfl_xor(mx, 8));
        float s = 0.f;
#pragma unroll
        for (int nf = 0; nf < 4; ++nf) { p[r][nf] = __expf(p[r][nf] - mx); s += p[r][nf]; }
        s += __shfl_xor(s, 1);
        s += __shfl_xor(s, 2);
        s += __shfl_xor(s, 4);
        s += __shfl_xor(s, 8);
        inv[r] = 1.0f / s;
    }

    float part[4];
#pragma unroll
    for (int nf = 0; nf < 4; ++nf) {
        float a = 0.f;
#pragma unroll
        for (int r = 0; r < 4; ++r) {
            const int row = wv * 16 + lq * 4 + r;
            a = fmaf(coef_s[row] * inv[r], p[r][nf], a);
        }
        part[nf] = a;
    }
#pragma unroll
    for (int nf = 0; nf < 4; ++nf) {
        part[nf] += __shfl_xor(part[nf], 16);
        part[nf] += __shfl_xor(part[nf], 32);
    }
    if (lq == 0)
#pragma unroll
        for (int nf = 0; nf < 4; ++nf) wpart[wv][nf * 16 + lr] = part[nf];
    __syncthreads();
    if (tid < Cc)
        wsum_s[tid] = wpart[0][tid] + wpart[1][tid] + wpart[2][tid] + wpart[3][tid];
    __syncthreads();

    float a3 = 0.f;
#pragma unroll 8
    for (int d = 0; d < Cc; ++d)
        a3 = fmaf(wsum_s[d], emb_table[(size_t)codes_l[d] * Ee + tid], a3);
    vv[(v * Bb + b) * Ee + tid] = a3;
}

// ---------------------------------------------------------------------------
// Kernel 2: merged fwd+bwd x@W^T. blockIdx.x<25 -> forward; ==25 -> backward.
// ---------------------------------------------------------------------------
__global__ __launch_bounds__(256) void xw_kernel(
    const float* __restrict__ vv,
    const float* __restrict__ w_ih_f, const float* __restrict__ b_ih_f,
    const float* __restrict__ b_hh_f,
    const float* __restrict__ w_ih_b, const float* __restrict__ b_ih_b,
    const float* __restrict__ b_hh_b,
    float* __restrict__ xg_f, float* __restrict__ xgb)
{
    const bool bwd = (blockIdx.x == 25);
    const float* A  = bwd ? (vv + 49 * Bb * Ee) : vv;
    const float* W  = bwd ? w_ih_b : w_ih_f;
    const float* b1 = bwd ? b_ih_b : b_ih_f;
    const float* b2 = bwd ? b_hh_b : b_hh_f;
    float* Cout     = bwd ? xgb : xg_f;
    const int M     = bwd ? Bb : BVn;
    const int m0    = bwd ? 0 : blockIdx.x * 64;
    const int j0    = blockIdx.y * 64;

    __shared__ float a_s[64 * 65];
    __shared__ float w_s[64 * 65];
    const int tid = threadIdx.x, tx = tid & 15, ty = tid >> 4;
    float acc[4][4] = {};
    for (int kc = 0; kc < 256; kc += 64) {
        __syncthreads();
        for (int idx = tid; idx < 4096; idx += 256) {
            int r = idx >> 6, kk = idx & 63;
            int m = m0 + r;
            a_s[r * 65 + kk] = (m < M) ? A[m * 256 + kc + kk] : 0.f;
            w_s[r * 65 + kk] = W[(j0 + r) * 256 + kc + kk];
        }
        __syncthreads();
#pragma unroll 8
        for (int kk = 0; kk < 64; ++kk) {
            float av[4], wv[4];
#pragma unroll
            for (int i = 0; i < 4; ++i) av[i] = a_s[(ty * 4 + i) * 65 + kk];
#pragma unroll
            for (int j = 0; j < 4; ++j) wv[j] = w_s[(tx * 4 + j) * 65 + kk];
#pragma unroll
            for (int i = 0; i < 4; ++i)
#pragma unroll
                for (int j = 0; j < 4; ++j)
                    acc[i][j] = fmaf(av[i], wv[j], acc[i][j]);
        }
    }
#pragma unroll
    for (int i = 0; i < 4; ++i) {
        int m = m0 + ty * 4 + i;
        if (m < M) {
#pragma unroll
            for (int j = 0; j < 4; ++j) {
                int jj = j0 + tx * 4 + j;
                Cout[m * 1024 + jj] = acc[i][j] + b1[jj] + b2[jj];
            }
        }
    }
}

// ---------------------------------------------------------------------------
// Kernel 3: persistent forward-LSTM. 8 blocks x 256 threads.
// r5 changes: 8 pollers/block on line-strided flags; acquire FENCE once,
// then plain coalesced f32x4 h-exchange loads (no per-element atomics).
// ---------------------------------------------------------------------------
__global__ __launch_bounds__(256) void lstm_persist(
    const float* __restrict__ xg,     // [50][32][1024]
    const float* __restrict__ w_hh,   // [1024][256] row-major
    float*       __restrict__ last_f, // [32][256]
    unsigned long long* __restrict__ hbuf,   // [2][32][64] u64 (4xbf16)
    unsigned*    __restrict__ flags)  // [NB*FSTR], flag i at i*FSTR
{
    __shared__ __align__(16) __bf16 w_s[RWS * WPAD];   // 66 KB
    __shared__ __align__(16) __bf16 h_s[Bb * WPAD];    // 16.5 KB
    __shared__ __align__(16) float  g_s[Bb * GPAD];    // 16.5 KB
    __shared__ __align__(16) float  c_s[Bb * CPAD];    // 4.5 KB

    const int tid = threadIdx.x, blk = blockIdx.x;
    const int hs0 = blk * HS;

    for (int i = tid; i < RWS * Ee; i += 256) {
        int r = i >> 8, k = i & 255;
        int grow = (r >> 5) * Hh + hs0 + (r & 31);
        w_s[r * WPAD + k] = (__bf16)w_hh[grow * Hh + k];
    }
    for (int i = tid; i < Bb * CPAD; i += 256) c_s[i] = 0.f;
    __syncthreads();

    const int l  = tid & 63, wvi = tid >> 6;
    const int lr = l & 15,   lq  = l >> 4;
    const int b_nl = tid >> 3, jg = tid & 7;
    const int col = hs0 + jg * 4;

    // prefetch xg(0)
    const float* x0 = xg + (size_t)b_nl * 1024;
    f32x4 ngi = *(const f32x4*)&x0[0 * Hh + col];
    f32x4 ngf = *(const f32x4*)&x0[1 * Hh + col];
    f32x4 ngg = *(const f32x4*)&x0[2 * Hh + col];
    f32x4 ngo = *(const f32x4*)&x0[3 * Hh + col];

    for (int t = 0; t < Vv; ++t) {
        if (t > 0) {
            // ---- 8 pollers only, one per producer, line-strided flags ----
            if (tid < NB) {
                int guard = 0;
                while (__hip_atomic_load(&flags[tid * FSTR], __ATOMIC_RELAXED,
                                         __HIP_MEMORY_SCOPE_AGENT) < (unsigned)t &&
                       ++guard < (1 << 27)) {
                    __builtin_amdgcn_s_sleep(1);
                }
            }
            __syncthreads();
            // one acquire fence: invalidate L1/L2 so plain loads see fresh data
            __builtin_amdgcn_fence(__ATOMIC_ACQUIRE, "agent");

            // ---- plain coalesced h-exchange load: 16 KB as f32x4 ----
            {
                const f32x4* hb = (const f32x4*)(hbuf + (t & 1) * (Bb * 64));
#pragma unroll
                for (int q = 0; q < 4; ++q) {
                    int i = tid + 256 * q;          // 0..1023
                    int batch = i >> 5, c16 = i & 31;
                    ((f32x4*)&h_s[batch * WPAD])[c16] = hb[batch * 32 + c16];
                }
            }
            __syncthreads();

            // ---- G[32][128] = h[32][256] @ w_slice^T ----
            f32x4 a00 = {}, a01 = {}, a10 = {}, a11 = {};
#pragma unroll
            for (int kt = 0; kt < 8; ++kt) {
                int ko = kt * 32 + lq * 8;
                bf16x8 A0 = *(const bf16x8*)&h_s[lr * WPAD + ko];
                bf16x8 A1 = *(const bf16x8*)&h_s[(16 + lr) * WPAD + ko];
                bf16x8 B0 = *(const bf16x8*)&w_s[(wvi * 32 + lr) * WPAD + ko];
                bf16x8 B1 = *(const bf16x8*)&w_s[(wvi * 32 + 16 + lr) * WPAD + ko];
                a00 = __builtin_amdgcn_mfma_f32_16x16x32_bf16(A0, B0, a00, 0, 0, 0);
                a01 = __builtin_amdgcn_mfma_f32_16x16x32_bf16(A0, B1, a01, 0, 0, 0);
                a10 = __builtin_amdgcn_mfma_f32_16x16x32_bf16(A1, B0, a10, 0, 0, 0);
                a11 = __builtin_amdgcn_mfma_f32_16x16x32_bf16(A1, B1, a11, 0, 0, 0);
            }
#pragma unroll
            for (int r = 0; r < 4; ++r) {
                int b0 = lq * 4 + r;
                g_s[b0 * GPAD + wvi * 32 + lr]             = a00[r];
                g_s[b0 * GPAD + wvi * 32 + 16 + lr]        = a01[r];
                g_s[(16 + b0) * GPAD + wvi * 32 + lr]      = a10[r];
                g_s[(16 + b0) * GPAD + wvi * 32 + 16 + lr] = a11[r];
            }
            __syncthreads();
        }

        // ---- nonlinearity (prefetched xg(t)); prefetch t+1 ----
        {
            f32x4 gi = ngi, gf = ngf, gg = ngg, go = ngo;
            if (t + 1 < Vv) {
                const float* nx = xg + ((size_t)(t + 1) * Bb + b_nl) * 1024;
                ngi = *(const f32x4*)&nx[0 * Hh + col];
                ngf = *(const f32x4*)&nx[1 * Hh + col];
                ngg = *(const f32x4*)&nx[2 * Hh + col];
                ngo = *(const f32x4*)&nx[3 * Hh + col];
            }
            if (t > 0) {
                int gb = b_nl * GPAD + jg * 4;
                gi += *(const f32x4*)&g_s[gb + 0 * HS];
                gf += *(const f32x4*)&g_s[gb + 1 * HS];
                gg += *(const f32x4*)&g_s[gb + 2 * HS];
                go += *(const f32x4*)&g_s[gb + 3 * HS];
            }
            f32x4 cv = *(const f32x4*)&c_s[b_nl * CPAD + jg * 4];
            float hnew[4];
#pragma unroll
            for (int u = 0; u < 4; ++u) {
                float iv = sigmoidf_(gi[u]);
                float fv = sigmoidf_(gf[u]);
                float gv = tanhf_(gg[u]);
                float ov = sigmoidf_(go[u]);
                float cn = fv * cv[u] + iv * gv;
                cv[u] = cn;
                hnew[u] = ov * tanhf_(cn);
            }
            *(f32x4*)&c_s[b_nl * CPAD + jg * 4] = cv;

            if (t < Vv - 1) {
                unsigned u0 =
                    ((unsigned)__builtin_bit_cast(unsigned short, (__bf16)hnew[0])) |
                    ((unsigned)__builtin_bit_cast(unsigned short, (__bf16)hnew[1]) << 16);
                unsigned u1 =
                    ((unsigned)__builtin_bit_cast(unsigned short, (__bf16)hnew[2])) |
                    ((unsigned)__builtin_bit_cast(unsigned short, (__bf16)hnew[3]) << 16);
                unsigned long long hv = (unsigned long long)u0 |
                                        ((unsigned long long)u1 << 32);
                int base = b_nl * 64 + blk * 8 + jg;
                __hip_atomic_store(hbuf + ((t + 1) & 1) * (Bb * 64) + base, hv,
                                   __ATOMIC_RELAXED, __HIP_MEMORY_SCOPE_AGENT);
            } else {
                f32x4 hv = {hnew[0], hnew[1], hnew[2], hnew[3]};
                *(f32x4*)&last_f[b_nl * Hh + hs0 + jg * 4] = hv;
            }
        }

        if (t < Vv - 1) {
            // barrier drains vmcnt for ALL waves -> h stores are L3-visible
            __syncthreads();
            if (tid == 0) {
                __hip_atomic_store(&flags[blk * FSTR], (unsigned)(t + 1),
                                   __ATOMIC_RELEASE, __HIP_MEMORY_SCOPE_AGENT);
            }
        }
    }
}

// ---------------------------------------------------------------------------
// Kernel 4: tail — backward single cell + head + softmax.
// ---------------------------------------------------------------------------
__global__ __launch_bounds__(512) void lstm_tail(
    const float* __restrict__ last_f,
    const float* __restrict__ xgb,
    const float* __restrict__ W_out,
    const float* __restrict__ b_out,
    float*       __restrict__ out)
{
    __shared__ float last_s[2 * Hh];
    __shared__ float logits_s[Ll];
    const int b = blockIdx.x, tid = threadIdx.x;

    if (tid < Hh) {
        last_s[tid] = last_f[b * Hh + tid];
    } else {
        int j = tid - Hh;
        float ig = sigmoidf_(xgb[b * 1024 + j]);
        float gg = tanhf_(xgb[b * 1024 + 2 * Hh + j]);
        float og = sigmoidf_(xgb[b * 1024 + 3 * Hh + j]);
        last_s[Hh + j] = og * tanhf_(ig * gg);
    }
    __syncthreads();

    if (tid < Ll) {
        float acc = b_out[tid];
        for (int q = 0; q < 2 * Hh; ++q)
            acc = fmaf(last_s[q], W_out[tid * 2 * Hh + q], acc);
        logits_s[tid] = acc;
    }
    __syncthreads();
    if (tid == 0) {
        float mx = -3.0e38f;
        for (int i = 0; i < Ll; ++i) mx = fmaxf(mx, logits_s[i]);
        float ex[Ll], s = 0.f;
        for (int i = 0; i < Ll; ++i) { ex[i] = __expf(logits_s[i] - mx); s += ex[i]; }
        float inv = 1.0f / s;
        for (int i = 0; i < Ll; ++i) out[b * Ll + i] = ex[i] * inv;
    }
}

// ---------------------------------------------------------------------------
extern "C" void kernel_launch(void* const* d_in, const int* in_sizes, int n_in,
                              void* d_out, int out_size, void* d_ws, size_t ws_size,
                              hipStream_t stream) {
    const int*   codes     = (const int*)  d_in[0];
    const float* mask      = (const float*)d_in[1];
    const float* tvals     = (const float*)d_in[2];
    const float* emb_table = (const float*)d_in[4];
    const float* WQ1       = (const float*)d_in[5];
    const float* WK1       = (const float*)d_in[6];
    const float* decay     = (const float*)d_in[7];
    const float* initial   = (const float*)d_in[8];
    const float* w_ih_f    = (const float*)d_in[9];
    const float* w_hh_f    = (const float*)d_in[10];
    const float* b_ih_f    = (const float*)d_in[11];
    const float* b_hh_f    = (const float*)d_in[12];
    const float* w_ih_b    = (const float*)d_in[13];
    // d_in[14] = w_hh_b: unused (backward output = first scan step, h0=c0=0)
    const float* b_ih_b    = (const float*)d_in[15];
    const float* b_hh_b    = (const float*)d_in[16];
    const float* W_out     = (const float*)d_in[17];
    const float* b_out     = (const float*)d_in[18];
    float* out = (float*)d_out;

    // workspace layout
    float* ws      = (float*)d_ws;
    float* vv      = ws;                 // 409600 f
    float* xg_f    = vv + 409600;        // 1638400 f
    float* xgb     = xg_f + 1638400;     // 32768 f
    float* last_f  = xgb + 32768;        // 8192 f
    __bf16* wqhi   = (__bf16*)(last_f + 8192);
    __bf16* wqlo   = wqhi + 32768;
    __bf16* wkhi   = wqlo + 32768;
    __bf16* wklo   = wkhi + 32768;
    unsigned long long* hbuf = (unsigned long long*)(wklo + 32768); // 4096 u64
    unsigned* flags = (unsigned*)(hbuf + 4096);                     // NB*FSTR u32

    wsplit<<<256, 256, 0, stream>>>(WQ1, WK1, wqhi, wqlo, wkhi, wklo, flags);
    attn_v2<<<BVn, 256, 0, stream>>>(codes, mask, tvals, emb_table,
                                     wqhi, wqlo, wkhi, wklo,
                                     decay, initial, vv);
    xw_kernel<<<dim3(26, 16), 256, 0, stream>>>(vv, w_ih_f, b_ih_f, b_hh_f,
                                                w_ih_b, b_ih_b, b_hh_b,
                                                xg_f, xgb);
    lstm_persist<<<NB, 256, 0, stream>>>(xg_f, w_hh_f, last_f, hbuf, flags);
    lstm_tail<<<Bb, 512, 0, stream>>>(last_f, xgb, W_out, b_out, out);
}

// Round 6
// 329.794 us; speedup vs baseline: 3.9496x; 1.0498x over previous
//
#include <hip/hip_runtime.h>
#include <hip/hip_bf16.h>
#include <math.h>

// Problem constants (from reference)
#define Bb 32
#define Vv 50
#define Cc 64
#define Ee 256
#define Aa 128
#define Hh 256
#define Ll 10
#define BVn (Bb*Vv)          // 1600
#define SCALE 0.08838834764831845f   // 1/sqrt(128)

// persistent-LSTM config
#define NB 8          // blocks
#define HS 32         // hidden units per block
#define RWS (4*HS)    // gate rows per block = 128
#define WPAD 264      // bf16 row stride
#define GPAD 132      // f32 row stride for gates scratch
#define CPAD 36       // f32 row stride for c state
#define FSTR 64       // flag stride in u32 (256 B -> one cache line per flag)

// attn LDS strides (bf16 elements)
#define EPAD 264
#define QPAD 136

typedef __bf16 bf16x8 __attribute__((ext_vector_type(8)));
typedef float  f32x4  __attribute__((ext_vector_type(4)));

__device__ __forceinline__ float sigmoidf_(float x) {
    return 1.0f / (1.0f + __expf(-x));
}
__device__ __forceinline__ float tanhf_(float x) {
    return 1.0f - 2.0f / (__expf(2.0f * x) + 1.0f);
}

// ---------------------------------------------------------------------------
// Kernel 0: decompose WQ1/WK1 into bf16 hi/lo pairs; block 0 zeroes sync flags
// ---------------------------------------------------------------------------
__global__ __launch_bounds__(256) void wsplit(
    const float* __restrict__ wq, const float* __restrict__ wk,
    __bf16* __restrict__ qh, __bf16* __restrict__ ql,
    __bf16* __restrict__ kh, __bf16* __restrict__ kl,
    unsigned* __restrict__ flags)
{
    if (blockIdx.x == 0) {
        for (int i = threadIdx.x; i < NB * FSTR; i += 256)
            __hip_atomic_store(&flags[i], 0u, __ATOMIC_RELAXED,
                               __HIP_MEMORY_SCOPE_AGENT);
    }
    int i = blockIdx.x * 256 + threadIdx.x;    // 0..65535
    if (i < 32768) {
        float f = wq[i];
        __bf16 h = (__bf16)f;
        qh[i] = h; ql[i] = (__bf16)(f - (float)h);
    } else {
        int j = i - 32768;
        float f = wk[j];
        __bf16 h = (__bf16)f;
        kh[j] = h; kl[j] = (__bf16)(f - (float)h);
    }
}

// ---------------------------------------------------------------------------
// Kernel 1: attention — split-bf16 MFMA, in-register softmax. (unchanged)
// ---------------------------------------------------------------------------
__global__ __launch_bounds__(256, 2) void attn_v2(
    const int*   __restrict__ codes,
    const float* __restrict__ mask,
    const float* __restrict__ tvals,
    const float* __restrict__ emb_table,
    const __bf16* __restrict__ wqhi, const __bf16* __restrict__ wqlo,
    const __bf16* __restrict__ wkhi, const __bf16* __restrict__ wklo,
    const float* __restrict__ decay,
    const float* __restrict__ initial,
    float*       __restrict__ vv)
{
    __shared__ __align__(16) __bf16 buf[4 * Cc * QPAD];
    __shared__ int   codes_l[Cc];
    __shared__ float maskcol_s[Cc], coef_s[Cc], wsum_s[Cc];
    __shared__ float wpart[4][Cc];

    __bf16* ehi = buf;
    __bf16* elo = buf + Cc * EPAD;
    __bf16* qhi = buf;
    __bf16* qlo = buf + 1 * Cc * QPAD;
    __bf16* khi = buf + 2 * Cc * QPAD;
    __bf16* klo = buf + 3 * Cc * QPAD;

    const int n   = blockIdx.x;
    const int tid = threadIdx.x;
    const int b   = n / Vv;
    const int v   = n - b * Vv;
    const int wv  = tid >> 6;
    const int lane = tid & 63;
    const int lr  = lane & 15;
    const int lq  = lane >> 4;

    if (tid < Cc) {
        codes_l[tid]   = codes[n * Cc + tid];
        maskcol_s[tid] = mask[n * Cc + tid];
    }
    __syncthreads();

    for (int i = tid; i < Cc * Ee; i += 256) {
        int c = i >> 8, e = i & 255;
        float f = emb_table[(size_t)codes_l[c] * Ee + e];
        __bf16 h = (__bf16)f;
        ehi[c * EPAD + e] = h;
        elo[c * EPAD + e] = (__bf16)(f - (float)h);
    }
    if (tid < Cc) {
        int code = codes_l[tid];
        float keep = (maskcol_s[tid] == 0.0f) ? 1.0f : 0.0f;
        coef_s[tid] = keep * sigmoidf_(decay[code] * tvals[n] + initial[code]);
    }
    __syncthreads();

    const __bf16* bh = (wv < 2) ? wqhi : wkhi;
    const __bf16* bl = (wv < 2) ? wqlo : wklo;
    const int colbase = (wv & 1) * 64;

    f32x4 acc[4][4] = {};
    for (int kt = 0; kt < 8; ++kt) {
        const int k0 = kt * 32 + lq * 8;
        bf16x8 Ahh[4], All[4], Bhh[4], Bll[4];
#pragma unroll
        for (int mf = 0; mf < 4; ++mf) {
            Ahh[mf] = *(const bf16x8*)&ehi[(mf * 16 + lr) * EPAD + k0];
            All[mf] = *(const bf16x8*)&elo[(mf * 16 + lr) * EPAD + k0];
        }
#pragma unroll
        for (int nf = 0; nf < 4; ++nf) {
            const int row = colbase + nf * 16 + lr;
            Bhh[nf] = *(const bf16x8*)&bh[row * Ee + k0];
            Bll[nf] = *(const bf16x8*)&bl[row * Ee + k0];
        }
#pragma unroll
        for (int mf = 0; mf < 4; ++mf)
#pragma unroll
            for (int nf = 0; nf < 4; ++nf) {
                acc[mf][nf] = __builtin_amdgcn_mfma_f32_16x16x32_bf16(Ahh[mf], Bhh[nf], acc[mf][nf], 0, 0, 0);
                acc[mf][nf] = __builtin_amdgcn_mfma_f32_16x16x32_bf16(Ahh[mf], Bll[nf], acc[mf][nf], 0, 0, 0);
                acc[mf][nf] = __builtin_amdgcn_mfma_f32_16x16x32_bf16(All[mf], Bhh[nf], acc[mf][nf], 0, 0, 0);
            }
    }
    __syncthreads();

    {
        __bf16* dh = (wv < 2) ? qhi : khi;
        __bf16* dl = (wv < 2) ? qlo : klo;
#pragma unroll
        for (int mf = 0; mf < 4; ++mf)
#pragma unroll
            for (int nf = 0; nf < 4; ++nf) {
                const int colb = colbase + nf * 16 + lr;
#pragma unroll
                for (int r = 0; r < 4; ++r) {
                    const int m = mf * 16 + lq * 4 + r;
                    float q = acc[mf][nf][r];
                    __bf16 h = (__bf16)q;
                    dh[m * QPAD + colb] = h;
                    dl[m * QPAD + colb] = (__bf16)(q - (float)h);
                }
            }
    }
    __syncthreads();

    f32x4 dacc[4] = {};
    for (int kt = 0; kt < 4; ++kt) {
        const int k0 = kt * 32 + lq * 8;
        bf16x8 Ahh = *(const bf16x8*)&qhi[(wv * 16 + lr) * QPAD + k0];
        bf16x8 All = *(const bf16x8*)&qlo[(wv * 16 + lr) * QPAD + k0];
#pragma unroll
        for (int nf = 0; nf < 4; ++nf) {
            bf16x8 Bhh = *(const bf16x8*)&khi[(nf * 16 + lr) * QPAD + k0];
            bf16x8 Bll = *(const bf16x8*)&klo[(nf * 16 + lr) * QPAD + k0];
            dacc[nf] = __builtin_amdgcn_mfma_f32_16x16x32_bf16(Ahh, Bhh, dacc[nf], 0, 0, 0);
            dacc[nf] = __builtin_amdgcn_mfma_f32_16x16x32_bf16(Ahh, Bll, dacc[nf], 0, 0, 0);
            dacc[nf] = __builtin_amdgcn_mfma_f32_16x16x32_bf16(All, Bhh, dacc[nf], 0, 0, 0);
        }
    }

    float p[4][4], inv[4];
#pragma unroll
    for (int r = 0; r < 4; ++r) {
#pragma unroll
        for (int nf = 0; nf < 4; ++nf)
            p[r][nf] = (dacc[nf][r] - maskcol_s[nf * 16 + lr]) * SCALE;
        float mx = fmaxf(fmaxf(p[r][0], p[r][1]), fmaxf(p[r][2], p[r][3]));
        mx = fmaxf(mx, __shfl_xor(mx, 1));
        mx = fmaxf(mx, __shfl_xor(mx, 2));
        mx = fmaxf(mx, __shfl_xor(mx, 4));
        mx = fmaxf(mx, __shfl_xor(mx, 8));
        float s = 0.f;
#pragma unroll
        for (int nf = 0; nf < 4; ++nf) { p[r][nf] = __expf(p[r][nf] - mx); s += p[r][nf]; }
        s += __shfl_xor(s, 1);
        s += __shfl_xor(s, 2);
        s += __shfl_xor(s, 4);
        s += __shfl_xor(s, 8);
        inv[r] = 1.0f / s;
    }

    float part[4];
#pragma unroll
    for (int nf = 0; nf < 4; ++nf) {
        float a = 0.f;
#pragma unroll
        for (int r = 0; r < 4; ++r) {
            const int row = wv * 16 + lq * 4 + r;
            a = fmaf(coef_s[row] * inv[r], p[r][nf], a);
        }
        part[nf] = a;
    }
#pragma unroll
    for (int nf = 0; nf < 4; ++nf) {
        part[nf] += __shfl_xor(part[nf], 16);
        part[nf] += __shfl_xor(part[nf], 32);
    }
    if (lq == 0)
#pragma unroll
        for (int nf = 0; nf < 4; ++nf) wpart[wv][nf * 16 + lr] = part[nf];
    __syncthreads();
    if (tid < Cc)
        wsum_s[tid] = wpart[0][tid] + wpart[1][tid] + wpart[2][tid] + wpart[3][tid];
    __syncthreads();

    float a3 = 0.f;
#pragma unroll 8
    for (int d = 0; d < Cc; ++d)
        a3 = fmaf(wsum_s[d], emb_table[(size_t)codes_l[d] * Ee + tid], a3);
    vv[(v * Bb + b) * Ee + tid] = a3;
}

// ---------------------------------------------------------------------------
// Kernel 2: merged fwd+bwd x@W^T. blockIdx.x<25 -> forward; ==25 -> backward.
// ---------------------------------------------------------------------------
__global__ __launch_bounds__(256) void xw_kernel(
    const float* __restrict__ vv,
    const float* __restrict__ w_ih_f, const float* __restrict__ b_ih_f,
    const float* __restrict__ b_hh_f,
    const float* __restrict__ w_ih_b, const float* __restrict__ b_ih_b,
    const float* __restrict__ b_hh_b,
    float* __restrict__ xg_f, float* __restrict__ xgb)
{
    const bool bwd = (blockIdx.x == 25);
    const float* A  = bwd ? (vv + 49 * Bb * Ee) : vv;
    const float* W  = bwd ? w_ih_b : w_ih_f;
    const float* b1 = bwd ? b_ih_b : b_ih_f;
    const float* b2 = bwd ? b_hh_b : b_hh_f;
    float* Cout     = bwd ? xgb : xg_f;
    const int M     = bwd ? Bb : BVn;
    const int m0    = bwd ? 0 : blockIdx.x * 64;
    const int j0    = blockIdx.y * 64;

    __shared__ float a_s[64 * 65];
    __shared__ float w_s[64 * 65];
    const int tid = threadIdx.x, tx = tid & 15, ty = tid >> 4;
    float acc[4][4] = {};
    for (int kc = 0; kc < 256; kc += 64) {
        __syncthreads();
        for (int idx = tid; idx < 4096; idx += 256) {
            int r = idx >> 6, kk = idx & 63;
            int m = m0 + r;
            a_s[r * 65 + kk] = (m < M) ? A[m * 256 + kc + kk] : 0.f;
            w_s[r * 65 + kk] = W[(j0 + r) * 256 + kc + kk];
        }
        __syncthreads();
#pragma unroll 8
        for (int kk = 0; kk < 64; ++kk) {
            float av[4], wv[4];
#pragma unroll
            for (int i = 0; i < 4; ++i) av[i] = a_s[(ty * 4 + i) * 65 + kk];
#pragma unroll
            for (int j = 0; j < 4; ++j) wv[j] = w_s[(tx * 4 + j) * 65 + kk];
#pragma unroll
            for (int i = 0; i < 4; ++i)
#pragma unroll
                for (int j = 0; j < 4; ++j)
                    acc[i][j] = fmaf(av[i], wv[j], acc[i][j]);
        }
    }
#pragma unroll
    for (int i = 0; i < 4; ++i) {
        int m = m0 + ty * 4 + i;
        if (m < M) {
#pragma unroll
            for (int j = 0; j < 4; ++j) {
                int jj = j0 + tx * 4 + j;
                Cout[m * 1024 + jj] = acc[i][j] + b1[jj] + b2[jj];
            }
        }
    }
}

// ---------------------------------------------------------------------------
// Kernel 3: persistent forward-LSTM. 8 blocks x 256 threads.
// r6 change: NO acquire fence (no L2 invalidate). h-exchange via coherent
// cache-bypass loads: global_load_dwordx4 sc0 sc1 reads the coherence point
// directly (128-bit analog of an agent-scope relaxed atomic load).
// ---------------------------------------------------------------------------
__global__ __launch_bounds__(256) void lstm_persist(
    const float* __restrict__ xg,     // [50][32][1024]
    const float* __restrict__ w_hh,   // [1024][256] row-major
    float*       __restrict__ last_f, // [32][256]
    unsigned long long* __restrict__ hbuf,   // [2][32][64] u64 (4xbf16)
    unsigned*    __restrict__ flags)  // [NB*FSTR], flag i at i*FSTR
{
    __shared__ __align__(16) __bf16 w_s[RWS * WPAD];   // 66 KB
    __shared__ __align__(16) __bf16 h_s[Bb * WPAD];    // 16.5 KB
    __shared__ __align__(16) float  g_s[Bb * GPAD];    // 16.5 KB
    __shared__ __align__(16) float  c_s[Bb * CPAD];    // 4.5 KB

    const int tid = threadIdx.x, blk = blockIdx.x;
    const int hs0 = blk * HS;

    for (int i = tid; i < RWS * Ee; i += 256) {
        int r = i >> 8, k = i & 255;
        int grow = (r >> 5) * Hh + hs0 + (r & 31);
        w_s[r * WPAD + k] = (__bf16)w_hh[grow * Hh + k];
    }
    for (int i = tid; i < Bb * CPAD; i += 256) c_s[i] = 0.f;
    __syncthreads();

    const int l  = tid & 63, wvi = tid >> 6;
    const int lr = l & 15,   lq  = l >> 4;
    const int b_nl = tid >> 3, jg = tid & 7;
    const int col = hs0 + jg * 4;

    // prefetch xg(0)
    const float* x0 = xg + (size_t)b_nl * 1024;
    f32x4 ngi = *(const f32x4*)&x0[0 * Hh + col];
    f32x4 ngf = *(const f32x4*)&x0[1 * Hh + col];
    f32x4 ngg = *(const f32x4*)&x0[2 * Hh + col];
    f32x4 ngo = *(const f32x4*)&x0[3 * Hh + col];

    for (int t = 0; t < Vv; ++t) {
        if (t > 0) {
            // ---- 8 pollers only, one per producer, line-strided flags ----
            if (tid < NB) {
                int guard = 0;
                while (__hip_atomic_load(&flags[tid * FSTR], __ATOMIC_RELAXED,
                                         __HIP_MEMORY_SCOPE_AGENT) < (unsigned)t &&
                       ++guard < (1 << 27)) {
                    __builtin_amdgcn_s_sleep(1);
                }
            }
            __syncthreads();

            // ---- coherent bypass h-exchange: 4x dwordx4 sc0 sc1, one wait ----
            {
                const char* hb = (const char*)(hbuf + (t & 1) * (Bb * 64));
                const char* a0 = hb + (size_t)(tid +   0) * 16;
                const char* a1 = hb + (size_t)(tid + 256) * 16;
                const char* a2 = hb + (size_t)(tid + 512) * 16;
                const char* a3 = hb + (size_t)(tid + 768) * 16;
                f32x4 h0, h1, h2, h3;
                asm volatile(
                    "global_load_dwordx4 %0, %4, off sc0 sc1\n\t"
                    "global_load_dwordx4 %1, %5, off sc0 sc1\n\t"
                    "global_load_dwordx4 %2, %6, off sc0 sc1\n\t"
                    "global_load_dwordx4 %3, %7, off sc0 sc1\n\t"
                    "s_waitcnt vmcnt(0)"
                    : "=&v"(h0), "=&v"(h1), "=&v"(h2), "=&v"(h3)
                    : "v"(a0), "v"(a1), "v"(a2), "v"(a3)
                    : "memory");
                __builtin_amdgcn_sched_barrier(0);
                // chunk i -> batch = i>>5, c16 = i&31  (row = 512 B)
                *(f32x4*)((char*)h_s + (size_t)((tid +   0) >> 5) * (WPAD * 2) + ((tid +   0) & 31) * 16) = h0;
                *(f32x4*)((char*)h_s + (size_t)((tid + 256) >> 5) * (WPAD * 2) + ((tid + 256) & 31) * 16) = h1;
                *(f32x4*)((char*)h_s + (size_t)((tid + 512) >> 5) * (WPAD * 2) + ((tid + 512) & 31) * 16) = h2;
                *(f32x4*)((char*)h_s + (size_t)((tid + 768) >> 5) * (WPAD * 2) + ((tid + 768) & 31) * 16) = h3;
            }
            __syncthreads();

            // ---- G[32][128] = h[32][256] @ w_slice^T ----
            f32x4 a00 = {}, a01 = {}, a10 = {}, a11 = {};
#pragma unroll
            for (int kt = 0; kt < 8; ++kt) {
                int ko = kt * 32 + lq * 8;
                bf16x8 A0 = *(const bf16x8*)&h_s[lr * WPAD + ko];
                bf16x8 A1 = *(const bf16x8*)&h_s[(16 + lr) * WPAD + ko];
                bf16x8 B0 = *(const bf16x8*)&w_s[(wvi * 32 + lr) * WPAD + ko];
                bf16x8 B1 = *(const bf16x8*)&w_s[(wvi * 32 + 16 + lr) * WPAD + ko];
                a00 = __builtin_amdgcn_mfma_f32_16x16x32_bf16(A0, B0, a00, 0, 0, 0);
                a01 = __builtin_amdgcn_mfma_f32_16x16x32_bf16(A0, B1, a01, 0, 0, 0);
                a10 = __builtin_amdgcn_mfma_f32_16x16x32_bf16(A1, B0, a10, 0, 0, 0);
                a11 = __builtin_amdgcn_mfma_f32_16x16x32_bf16(A1, B1, a11, 0, 0, 0);
            }
#pragma unroll
            for (int r = 0; r < 4; ++r) {
                int b0 = lq * 4 + r;
                g_s[b0 * GPAD + wvi * 32 + lr]             = a00[r];
                g_s[b0 * GPAD + wvi * 32 + 16 + lr]        = a01[r];
                g_s[(16 + b0) * GPAD + wvi * 32 + lr]      = a10[r];
                g_s[(16 + b0) * GPAD + wvi * 32 + 16 + lr] = a11[r];
            }
            __syncthreads();
        }

        // ---- nonlinearity (prefetched xg(t)); prefetch t+1 ----
        {
            f32x4 gi = ngi, gf = ngf, gg = ngg, go = ngo;
            if (t + 1 < Vv) {
                const float* nx = xg + ((size_t)(t + 1) * Bb + b_nl) * 1024;
                ngi = *(const f32x4*)&nx[0 * Hh + col];
                ngf = *(const f32x4*)&nx[1 * Hh + col];
                ngg = *(const f32x4*)&nx[2 * Hh + col];
                ngo = *(const f32x4*)&nx[3 * Hh + col];
            }
            if (t > 0) {
                int gb = b_nl * GPAD + jg * 4;
                gi += *(const f32x4*)&g_s[gb + 0 * HS];
                gf += *(const f32x4*)&g_s[gb + 1 * HS];
                gg += *(const f32x4*)&g_s[gb + 2 * HS];
                go += *(const f32x4*)&g_s[gb + 3 * HS];
            }
            f32x4 cv = *(const f32x4*)&c_s[b_nl * CPAD + jg * 4];
            float hnew[4];
#pragma unroll
            for (int u = 0; u < 4; ++u) {
                float iv = sigmoidf_(gi[u]);
                float fv = sigmoidf_(gf[u]);
                float gv = tanhf_(gg[u]);
                float ov = sigmoidf_(go[u]);
                float cn = fv * cv[u] + iv * gv;
                cv[u] = cn;
                hnew[u] = ov * tanhf_(cn);
            }
            *(f32x4*)&c_s[b_nl * CPAD + jg * 4] = cv;

            if (t < Vv - 1) {
                unsigned u0 =
                    ((unsigned)__builtin_bit_cast(unsigned short, (__bf16)hnew[0])) |
                    ((unsigned)__builtin_bit_cast(unsigned short, (__bf16)hnew[1]) << 16);
                unsigned u1 =
                    ((unsigned)__builtin_bit_cast(unsigned short, (__bf16)hnew[2])) |
                    ((unsigned)__builtin_bit_cast(unsigned short, (__bf16)hnew[3]) << 16);
                unsigned long long hv = (unsigned long long)u0 |
                                        ((unsigned long long)u1 << 32);
                int base = b_nl * 64 + blk * 8 + jg;
                __hip_atomic_store(hbuf + ((t + 1) & 1) * (Bb * 64) + base, hv,
                                   __ATOMIC_RELAXED, __HIP_MEMORY_SCOPE_AGENT);
            } else {
                f32x4 hv = {hnew[0], hnew[1], hnew[2], hnew[3]};
                *(f32x4*)&last_f[b_nl * Hh + hs0 + jg * 4] = hv;
            }
        }

        if (t < Vv - 1) {
            // barrier drains vmcnt for ALL waves -> h stores at coherence point
            __syncthreads();
            if (tid == 0) {
                __hip_atomic_store(&flags[blk * FSTR], (unsigned)(t + 1),
                                   __ATOMIC_RELEASE, __HIP_MEMORY_SCOPE_AGENT);
            }
        }
    }
}

// ---------------------------------------------------------------------------
// Kernel 4: tail — backward single cell + head + softmax.
// ---------------------------------------------------------------------------
__global__ __launch_bounds__(512) void lstm_tail(
    const float* __restrict__ last_f,
    const float* __restrict__ xgb,
    const float* __restrict__ W_out,
    const float* __restrict__ b_out,
    float*       __restrict__ out)
{
    __shared__ float last_s[2 * Hh];
    __shared__ float logits_s[Ll];
    const int b = blockIdx.x, tid = threadIdx.x;

    if (tid < Hh) {
        last_s[tid] = last_f[b * Hh + tid];
    } else {
        int j = tid - Hh;
        float ig = sigmoidf_(xgb[b * 1024 + j]);
        float gg = tanhf_(xgb[b * 1024 + 2 * Hh + j]);
        float og = sigmoidf_(xgb[b * 1024 + 3 * Hh + j]);
        last_s[Hh + j] = og * tanhf_(ig * gg);
    }
    __syncthreads();

    if (tid < Ll) {
        float acc = b_out[tid];
        for (int q = 0; q < 2 * Hh; ++q)
            acc = fmaf(last_s[q], W_out[tid * 2 * Hh + q], acc);
        logits_s[tid] = acc;
    }
    __syncthreads();
    if (tid == 0) {
        float mx = -3.0e38f;
        for (int i = 0; i < Ll; ++i) mx = fmaxf(mx, logits_s[i]);
        float ex[Ll], s = 0.f;
        for (int i = 0; i < Ll; ++i) { ex[i] = __expf(logits_s[i] - mx); s += ex[i]; }
        float inv = 1.0f / s;
        for (int i = 0; i < Ll; ++i) out[b * Ll + i] = ex[i] * inv;
    }
}

// ---------------------------------------------------------------------------
extern "C" void kernel_launch(void* const* d_in, const int* in_sizes, int n_in,
                              void* d_out, int out_size, void* d_ws, size_t ws_size,
                              hipStream_t stream) {
    const int*   codes     = (const int*)  d_in[0];
    const float* mask      = (const float*)d_in[1];
    const float* tvals     = (const float*)d_in[2];
    const float* emb_table = (const float*)d_in[4];
    const float* WQ1       = (const float*)d_in[5];
    const float* WK1       = (const float*)d_in[6];
    const float* decay     = (const float*)d_in[7];
    const float* initial   = (const float*)d_in[8];
    const float* w_ih_f    = (const float*)d_in[9];
    const float* w_hh_f    = (const float*)d_in[10];
    const float* b_ih_f    = (const float*)d_in[11];
    const float* b_hh_f    = (const float*)d_in[12];
    const float* w_ih_b    = (const float*)d_in[13];
    // d_in[14] = w_hh_b: unused (backward output = first scan step, h0=c0=0)
    const float* b_ih_b    = (const float*)d_in[15];
    const float* b_hh_b    = (const float*)d_in[16];
    const float* W_out     = (const float*)d_in[17];
    const float* b_out     = (const float*)d_in[18];
    float* out = (float*)d_out;

    // workspace layout
    float* ws      = (float*)d_ws;
    float* vv      = ws;                 // 409600 f
    float* xg_f    = vv + 409600;        // 1638400 f
    float* xgb     = xg_f + 1638400;     // 32768 f
    float* last_f  = xgb + 32768;        // 8192 f
    __bf16* wqhi   = (__bf16*)(last_f + 8192);
    __bf16* wqlo   = wqhi + 32768;
    __bf16* wkhi   = wqlo + 32768;
    __bf16* wklo   = wkhi + 32768;
    unsigned long long* hbuf = (unsigned long long*)(wklo + 32768); // 4096 u64
    unsigned* flags = (unsigned*)(hbuf + 4096);                     // NB*FSTR u32

    wsplit<<<256, 256, 0, stream>>>(WQ1, WK1, wqhi, wqlo, wkhi, wklo, flags);
    attn_v2<<<BVn, 256, 0, stream>>>(codes, mask, tvals, emb_table,
                                     wqhi, wqlo, wkhi, wklo,
                                     decay, initial, vv);
    xw_kernel<<<dim3(26, 16), 256, 0, stream>>>(vv, w_ih_f, b_ih_f, b_hh_f,
                                                w_ih_b, b_ih_b, b_hh_b,
                                                xg_f, xgb);
    lstm_persist<<<NB, 256, 0, stream>>>(xg_f, w_hh_f, last_f, hbuf, flags);
    lstm_tail<<<Bb, 512, 0, stream>>>(last_f, xgb, W_out, b_out, out);
}